// Round 14
// baseline (289.480 us; speedup 1.0000x reference)
//
#include <hip/hip_runtime.h>

#define NA      30000
#define MPAD    30080            // 235 * 128
#define NPAIRS  1200000
#define NB      7
#define NK      5
#define NSP     119
#define NFEAT   360
#define KP1     384              // NFEAT padded to 64
#define NU      512
#define WROW    36               // padded W row (35 -> 36 floats, 144B, 16B aligned)
#define MAXSLOT 120              // plist slots per atom (Poisson(40): P(deg>120) ~ 0)
#define PSTRIDE 128              // plist row stride in ints (alignment)
#define NBK     118              // coarse buckets of 256 atoms (ceil(30000/256))
#define BCAP    11520            // entries per coarse bucket (mean 10240, sd ~101)
#define PPB     4688             // pairs per partition block (256 blocks)
#define NTILE   235              // 128-atom tiles

#define BETTA      1.3611111111111112f     // 49/36
#define RADNORM    0.96481348f             // (2*betta/pi)^0.25
#define SHIFT_STEP 0.7857142857142857f     // 5.5/7
#define PI_OVER_R  0.5235987755982988f     // pi/6
#define INV_SQRT7  0.3779644730092272f
#define RMAXV      6.0f

typedef __attribute__((ext_vector_type(8))) short bf16x8;
typedef __attribute__((ext_vector_type(4))) float f32x4;

__device__ __forceinline__ unsigned short f2b(float x) {
    unsigned u = __float_as_uint(x);
    unsigned r = u + 0x7FFF + ((u >> 16) & 1);   // RNE (inputs are finite)
    return (unsigned short)(r >> 16);
}

// ---------------- phase 1: partition pairs into 118 coarse buckets ----------------
// entry pack: (i&255)<<22 | Zj<<15 | j   (iloc 8b, Zj 7b, j 15b)
__global__ __launch_bounds__(256)
void k_part(const int* __restrict__ idx, const int* __restrict__ Z,
            int* __restrict__ gcur, int* __restrict__ part) {
    __shared__ int hist[NBK];
    __shared__ int base[NBK];
    int tid = threadIdx.x;
    for (int b = tid; b < NBK; b += 256) hist[b] = 0;
    __syncthreads();
    int p0 = blockIdx.x * PPB;
    int p1 = min(p0 + PPB, NPAIRS);
    for (int p = p0 + tid; p < p1; p += 256)
        atomicAdd(&hist[idx[p] >> 8], 1);
    __syncthreads();
    for (int b = tid; b < NBK; b += 256) {
        base[b] = atomicAdd(&gcur[b], hist[b]);
        hist[b] = 0;
    }
    __syncthreads();
    for (int p = p0 + tid; p < p1; p += 256) {
        int i = idx[p];
        int b = i >> 8;
        int j = idx[NPAIRS + p];
        int zj = Z[j];
        int off = base[b] + atomicAdd(&hist[b], 1);
        if (off < BCAP)
            part[b * BCAP + off] = ((i & 255) << 22) | (zj << 15) | j;
    }
}

// ---------------- phase 2: coarse buckets -> dense CSR rows (coalesced writes) ----
__global__ __launch_bounds__(256)
void k_csr(const int* __restrict__ part, const int* __restrict__ gcnt,
           int* __restrict__ counts, int* __restrict__ plist) {
    __shared__ int lp[128 * MAXSLOT];   // 61440 B
    __shared__ int lc[128];
    int tid = threadIdx.x;
    int lane = tid & 63, wave = tid >> 6;
    int w = blockIdx.x;                 // 128-atom window, 0..234
    int cb = w >> 1;                    // coarse bucket
    int par = w & 1;                    // which 128-half of the 256-atom bucket
    for (int t = tid; t < 128; t += 256) lc[t] = 0;
    __syncthreads();
    int n = min(gcnt[cb], BCAP);
    for (int e = tid; e < n; e += 256) {
        int v = part[cb * BCAP + e];
        int iloc = v >> 22;             // 0..255
        if ((iloc >> 7) == par) {
            int i7 = iloc & 127;
            int r = atomicAdd(&lc[i7], 1);
            if (r < MAXSLOT) lp[i7 * MAXSLOT + r] = v & 0x3FFFFF;  // Zj<<15 | j
        }
    }
    __syncthreads();
    for (int t = tid; t < 128; t += 256) {
        int a = w * 128 + t;
        if (a < NA) counts[a] = min(lc[t], MAXSLOT);
    }
    // coalesced row writes: each wave 32 rows (4 waves x 32 = 128 rows)
    for (int rr = 0; rr < 32; rr++) {
        int row = wave * 32 + rr;
        int a = w * 128 + row;
        if (a < NA) {
            for (int c = lane; c < MAXSLOT; c += 64)
                plist[(size_t)a * PSTRIDE + c] = lp[row * MAXSLOT + c];
        }
    }
}

// ---------------- merged prep: Wpad, Rpad, w1T, w2T in one launch ----------------
#define PREP_W   (NSP*NSP*WROW)          // 509796
#define PREP_R   NA                      // 30000
#define PREP_W1  (NU*KP1)                // 196608
#define PREP_W2  (NU*NU)                 // 262144
#define PREP_TOT (PREP_W + PREP_R + PREP_W1 + PREP_W2)
__global__ void k_prep(const float* __restrict__ W, const float* __restrict__ R,
                       const float* __restrict__ w1, const float* __restrict__ w2,
                       float* __restrict__ Wp, float* __restrict__ Rp,
                       unsigned short* __restrict__ w1T, unsigned short* __restrict__ w2T) {
    int i = blockIdx.x * blockDim.x + threadIdx.x;
    if (i < PREP_W) {
        int row = i / WROW, e = i - row * WROW;
        Wp[i] = (e < NK * NB) ? W[row * (NK * NB) + e] : 0.f;
        return;
    }
    i -= PREP_W;
    if (i < PREP_R) {
        f32x4 v = {R[3*i], R[3*i+1], R[3*i+2], 0.f};
        *(f32x4*)&Rp[4*i] = v;
        return;
    }
    i -= PREP_R;
    if (i < PREP_W1) {
        int c = i / KP1, kp = i - c * KP1;
        w1T[i] = (kp < NFEAT) ? f2b(w1[kp * NU + c]) : (unsigned short)0;
        return;
    }
    i -= PREP_W1;
    if (i < PREP_W2) {
        int c = i >> 9, kp = i & 511;
        w2T[i] = f2b(w2[kp * NU + c]);
    }
}

// ------- fused moments+contraction: 16 lanes/atom, block = 16 atoms -------------
// Phase A: 16-lane groups gather pairs (7500 waves = 2x R11's TLP), accumulate
//          100 moments, butterfly-reduce (4 steps), lane q==0 -> MS[100][16] LDS.
// Phase B: contraction (4 waves split feature groups, lanes 0..15 = atoms),
//          results staged in FS[16][392] LDS, then one coalesced gmB write.
// NA = 30000 = 1875*16 exactly -> no partial block, no divergent-return barrier.
// NOTE 1 (R8): launch_bounds min-waves stays 2 — pinning 4 caps VGPRs at 128 and
//         spills acc[100] to scratch (685 MB scratch traffic, 5x slower).
// NOTE 2 (R9): acc[] only with compile-time indices — runtime-indexed access
//         demotes it to scratch (576 MB traffic). Lane q==0 writes all 100.
// NOTE 3 (R10): no pair-splitting into MULTIPLE groups (doubles epilogue+fetch);
//         a single wider group only adds one shfl step.
__global__ __launch_bounds__(256, 2)
void k_moments(const float* __restrict__ Rp, const int* __restrict__ Z,
               const float* __restrict__ Wp, const int* __restrict__ counts,
               const int* __restrict__ plist, unsigned short* __restrict__ gmB) {
    __shared__ float MS[100 * 17];             // 6800 B  [comp][16 atoms + pad]
    __shared__ unsigned short FS[16 * 392];    // 12544 B [atom][384 feats + pad]
    int tid = threadIdx.x;
    int g = tid >> 4, q = tid & 15;            // local atom, lane-in-group
    int a0 = blockIdx.x * 16;
    int a = a0 + g;                            // always < NA
    f32x4 ri = *(const f32x4*)&Rp[4*a];
    int Zi = Z[a];
    float acc[100];
#pragma unroll
    for (int u = 0; u < 100; u++) acc[u] = 0.f;
    int cnt = counts[a];
    const int* prow = plist + (size_t)a * PSTRIDE;

    for (int t = q; t < cnt; t += 16) {
        int pk = prow[t];
        int j  = pk & 0x7FFF;
        int Zj = (pk >> 15) & 0x7F;
        f32x4 rj = *(const f32x4*)&Rp[4*j];

        const f32x4* wrow = (const f32x4*)&Wp[(Zi * NSP + Zj) * WROW];
        f32x4 w4[9];
#pragma unroll
        for (int c = 0; c < 9; c++) w4[c] = wrow[c];
        const float* wf = (const float*)w4;

        float dx = rj.x - ri.x, dy = rj.y - ri.y, dz = rj.z - ri.z;
        float d2 = dx*dx + dy*dy + dz*dz + 1e-12f;
        float dr = sqrtf(d2);
        float inv = 1.0f / (dr + 1e-5f);
        float nx = dx*inv, ny = dy*inv, nz = dz*inv;

        float basis[NB];
#pragma unroll
        for (int b = 0; b < NB; b++) {
            float tt = dr - (0.5f + SHIFT_STEP * (float)b);
            basis[b] = RADNORM * __expf(-BETTA * tt * tt);
        }
        float cut = (dr < RMAXV) ? 0.5f * (__cosf(PI_OVER_R * dr) + 1.0f) : 0.0f;
        cut *= INV_SQRT7;
        float rad[NK];
#pragma unroll
        for (int k = 0; k < NK; k++) {
            float s = 0.f;
#pragma unroll
            for (int b = 0; b < NB; b++) s += wf[k*NB + b] * basis[b];
            rad[k] = s * cut;
        }
        float gg[20];
        gg[0] = 1.f; gg[1] = nx; gg[2] = ny; gg[3] = nz;
        gg[4] = nx*nx; gg[5] = nx*ny; gg[6] = nx*nz; gg[7] = ny*ny; gg[8] = ny*nz; gg[9] = nz*nz;
        gg[10] = gg[4]*nx; gg[11] = gg[4]*ny; gg[12] = gg[4]*nz; gg[13] = gg[5]*ny; gg[14] = gg[5]*nz;
        gg[15] = gg[6]*nz; gg[16] = gg[7]*ny; gg[17] = gg[7]*nz; gg[18] = gg[8]*nz; gg[19] = gg[9]*nz;
#pragma unroll
        for (int k = 0; k < NK; k++)
#pragma unroll
            for (int u = 0; u < 20; u++)
                acc[k*20 + u] += rad[k] * gg[u];
    }
    // butterfly reduce over the 16-lane group
#pragma unroll
    for (int u = 0; u < 100; u++) {
        float v = acc[u];
        v += __shfl_xor(v, 1);
        v += __shfl_xor(v, 2);
        v += __shfl_xor(v, 4);
        v += __shfl_xor(v, 8);
        acc[u] = v;
    }
    if (q == 0) {
#pragma unroll
        for (int u = 0; u < 100; u++) MS[u * 17 + g] = acc[u];
    }
    __syncthreads();

    // ---- contraction: waves split feature groups, lanes 0..15 = atoms ----
    int lane = tid & 63, wave = tid >> 6;
    int g16 = lane & 15;
    bool act = lane < 16;
    const int S2[3][3] = {{0,1,2},{1,3,4},{2,4,5}};
    const int S3[3][3][3] = {
        {{0,1,2},{1,3,4},{2,4,5}},
        {{1,3,4},{3,6,7},{4,7,8}},
        {{2,4,5},{4,7,8},{5,8,9}}
    };
    unsigned short* frow = &FS[g16 * 392];
#define LD(comp) MS[(comp) * 17 + g16]

    if (wave == 0) {
        if (act) {
            for (int k = 0; k < 5; k++) frow[k] = f2b(LD(k * 20));
        }
        int f = 5;
        for (int r = 0; r < 5; r++)
            for (int s = r; s < 5; s++) {
                float v = 0.f;
#pragma unroll
                for (int i = 0; i < 3; i++) v += LD(r*20+1+i) * LD(s*20+1+i);
                if (act) frow[f] = f2b(v);
                f++;
            }
        const float W2U[6] = {1,2,2,1,2,1};
        for (int r = 0; r < 5; r++)
            for (int s = r; s < 5; s++) {
                float v = 0.f;
#pragma unroll
                for (int u = 0; u < 6; u++) v += W2U[u] * LD(r*20+4+u) * LD(s*20+4+u);
                if (act) frow[f] = f2b(v);
                f++;
            }
        const float W3U[10] = {1,3,3,3,6,3,1,3,3,1};
        for (int r = 0; r < 5; r++)
            for (int s = r; s < 5; s++) {
                float v = 0.f;
#pragma unroll
                for (int u = 0; u < 10; u++) v += W3U[u] * LD(r*20+10+u) * LD(s*20+10+u);
                if (act) frow[f] = f2b(v);
                f++;
            }
        for (int r = 0; r < 5; r++) {
            float m2r[6];
#pragma unroll
            for (int u = 0; u < 6; u++) m2r[u] = LD(r*20+4+u);
            for (int s = r; s < 5; s++) {
                float m2q[6];
#pragma unroll
                for (int u = 0; u < 6; u++) m2q[u] = LD(s*20+4+u);
                for (int t = s; t < 5; t++) {
                    float m2t[6];
#pragma unroll
                    for (int u = 0; u < 6; u++) m2t[u] = LD(t*20+4+u);
                    float v = 0.f;
#pragma unroll
                    for (int i = 0; i < 3; i++)
#pragma unroll
                        for (int j = 0; j < 3; j++)
#pragma unroll
                            for (int k = 0; k < 3; k++)
                                v += m2r[S2[i][j]] * m2q[S2[i][k]] * m2t[S2[j][k]];
                    if (act) frow[f] = f2b(v);
                    f++;
                }
            }
        }
    } else if (wave == 1) {
        int f = 85;
        for (int r = 0; r < 5; r++) {
            float m1r[3];
#pragma unroll
            for (int i = 0; i < 3; i++) m1r[i] = LD(r*20+1+i);
            for (int s = r; s < 5; s++) {
                float m1q[3];
#pragma unroll
                for (int i = 0; i < 3; i++) m1q[i] = LD(s*20+1+i);
                for (int t = 0; t < 5; t++) {
                    float m2t[6];
#pragma unroll
                    for (int u = 0; u < 6; u++) m2t[u] = LD(t*20+4+u);
                    float v = 0.f;
#pragma unroll
                    for (int i = 0; i < 3; i++)
#pragma unroll
                        for (int j = 0; j < 3; j++)
                            v += m1r[i] * m1q[j] * m2t[S2[i][j]];
                    if (act) frow[f] = f2b(v);
                    f++;
                }
            }
        }
        f = 235;
        for (int r = 0; r < 5; r++) {
            float m3r[10];
#pragma unroll
            for (int u = 0; u < 10; u++) m3r[u] = LD(r*20+10+u);
            for (int s = 0; s < 5; s++) {
                float m2q[6];
#pragma unroll
                for (int u = 0; u < 6; u++) m2q[u] = LD(s*20+4+u);
                float U0 = 0.f, U1 = 0.f, U2 = 0.f;
#pragma unroll
                for (int i = 0; i < 3; i++)
#pragma unroll
                    for (int j = 0; j < 3; j++) {
                        float ww = m2q[S2[i][j]];
                        U0 += m3r[S3[i][j][0]] * ww;
                        U1 += m3r[S3[i][j][1]] * ww;
                        U2 += m3r[S3[i][j][2]] * ww;
                    }
                for (int t = 0; t < 5; t++) {
                    float v = U0 * LD(t*20+1) + U1 * LD(t*20+2) + U2 * LD(t*20+3);
                    if (act) frow[f] = f2b(v);
                    f++;
                }
            }
        }
    } else {
        int pbeg = (wave == 2) ? 0 : 7;
        int pend = (wave == 2) ? 7 : 15;
        int p = 0;
        for (int r = 0; r < 5; r++)
            for (int s = r; s < 5; s++) {
                if (p >= pbeg && p < pend) {
                    float m3r[10], m3q[10];
#pragma unroll
                    for (int u = 0; u < 10; u++) m3r[u] = LD(r*20+10+u);
#pragma unroll
                    for (int u = 0; u < 10; u++) m3q[u] = LD(s*20+10+u);
                    float T[3][3];
#pragma unroll
                    for (int k = 0; k < 3; k++)
#pragma unroll
                        for (int l = 0; l < 3; l++) {
                            float v = 0.f;
#pragma unroll
                            for (int i = 0; i < 3; i++)
#pragma unroll
                                for (int j = 0; j < 3; j++)
                                    v += m3r[S3[i][j][k]] * m3q[S3[i][j][l]];
                            T[k][l] = v;
                        }
                    int f = 160 + p * 5;
                    for (int t = 0; t < 5; t++) {
                        float m2t[6];
#pragma unroll
                        for (int u = 0; u < 6; u++) m2t[u] = LD(t*20+4+u);
                        float v = 0.f;
#pragma unroll
                        for (int k = 0; k < 3; k++)
#pragma unroll
                            for (int l = 0; l < 3; l++)
                                v += T[k][l] * m2t[S2[k][l]];
                        if (act) frow[f + t] = f2b(v);
                    }
                }
                p++;
            }
        if (wave == 3 && act) {
            for (int z = NFEAT; z < KP1; z++) frow[z] = 0;
        }
    }
#undef LD
    __syncthreads();
    // coalesced write-out: 16 atoms x 384 feats
    for (int e = tid; e < 16 * KP1; e += 256) {
        int at = e / KP1;
        int f = e - at * KP1;
        gmB[(size_t)(a0 + at) * KP1 + f] = FS[at * 392 + f];
    }
}

// ---------------- MFMA GEMM, persistent 2 atom-tiles per block -------------------
// MODE 1: A=atoms(gmB), B=units(w1T); h1B bf16 [MPAD][512] = swish(D + bias[col]),
//         written via LDS-staged coalesced stores.
// MODE 2: A=units(w2T), B=atoms(h1B); fused layer-3: atomicAdd w3[c]*swish(D+bias[c])
__device__ __forceinline__ void stage8(const unsigned short* gp, unsigned short* lp) {
    __builtin_amdgcn_global_load_lds(
        (const __attribute__((address_space(1))) unsigned int*)gp,
        (__attribute__((address_space(3))) unsigned int*)lp, 16, 0, 0);
}

template<int KPAD, int MODE>
__global__ __launch_bounds__(256) void k_mfma(const unsigned short* __restrict__ A,
                                              const unsigned short* __restrict__ B,
                                              const float* __restrict__ bias,
                                              const float* __restrict__ w3,
                                              void* __restrict__ outp) {
    // SMEM union: [As 16KB | Bs 16KB | red 1KB]  or  [Ot 128x136 shorts = 34816B]
    __shared__ __align__(16) unsigned char SMEM[35072];
    unsigned short* As = (unsigned short*)SMEM;
    unsigned short* Bs = (unsigned short*)(SMEM + 16384);
    float* red = (float*)(SMEM + 32768);       // [2][2][4][16]
    int tid = threadIdx.x;
    int lane = tid & 63, wave = tid >> 6;
    int wm = wave >> 1, wn = wave & 1;
    int quad = lane >> 4, l16 = lane & 15;
    int lrow = lane >> 3;          // 0..7
    int lchk = lane & 7;           // 16B chunk slot

    for (int t = 0; t < 2; t++) {
        int atile = blockIdx.y * 2 + t;
        if (atile >= NTILE) break;
        int rowA0, rowB0;
        if (MODE == 1) { rowA0 = atile * 128;      rowB0 = blockIdx.x * 128; }
        else           { rowA0 = blockIdx.x * 128; rowB0 = atile * 128; }

        f32x4 acc[4][4];
        f32x4 zero = {0.f, 0.f, 0.f, 0.f};
#pragma unroll
        for (int i = 0; i < 4; i++)
#pragma unroll
            for (int j = 0; j < 4; j++) acc[i][j] = zero;

        for (int k0 = 0; k0 < KPAD; k0 += 64) {
            __syncthreads();
#pragma unroll
            for (int i = 0; i < 4; i++) {
                int r = wave * 32 + i * 8 + lrow;
                int gc = lchk ^ (r & 7);
                stage8(A + (size_t)(rowA0 + r) * KPAD + k0 + gc * 8, &As[(wave * 32 + i * 8) * 64]);
            }
#pragma unroll
            for (int i = 0; i < 4; i++) {
                int r = wave * 32 + i * 8 + lrow;
                int gc = lchk ^ (r & 7);
                stage8(B + (size_t)(rowB0 + r) * KPAD + k0 + gc * 8, &Bs[(wave * 32 + i * 8) * 64]);
            }
            __syncthreads();
#pragma unroll
            for (int s = 0; s < 2; s++) {
                bf16x8 af[4], bfr[4];
#pragma unroll
                for (int mt = 0; mt < 4; mt++) {
                    int r = wm * 64 + mt * 16 + l16;
                    af[mt] = *(const bf16x8*)&As[r * 64 + (((s * 4 + quad) ^ (r & 7)) * 8)];
                }
#pragma unroll
                for (int nt = 0; nt < 4; nt++) {
                    int r = wn * 64 + nt * 16 + l16;
                    bfr[nt] = *(const bf16x8*)&Bs[r * 64 + (((s * 4 + quad) ^ (r & 7)) * 8)];
                }
#pragma unroll
                for (int mt = 0; mt < 4; mt++)
#pragma unroll
                    for (int nt = 0; nt < 4; nt++)
                        acc[mt][nt] = __builtin_amdgcn_mfma_f32_16x16x32_bf16(
                            af[mt], bfr[nt], acc[mt][nt], 0, 0, 0);
            }
        }

        if (MODE == 1) {
            // stage swish output tile in LDS (stride 136 shorts), then coalesced store
            __syncthreads();   // all waves done reading As/Bs
            unsigned short* Ot = (unsigned short*)SMEM;
#pragma unroll
            for (int nt = 0; nt < 4; nt++) {
                int c_loc = wn * 64 + nt * 16 + l16;
                float b = bias[rowB0 + c_loc];
#pragma unroll
                for (int mt = 0; mt < 4; mt++) {
#pragma unroll
                    for (int reg = 0; reg < 4; reg++) {
                        int a_loc = wm * 64 + mt * 16 + quad * 4 + reg;
                        float v = acc[mt][nt][reg] + b;
                        Ot[a_loc * 136 + c_loc] = f2b(v / (1.f + __expf(-v)));
                    }
                }
            }
            __syncthreads();
            unsigned short* O = (unsigned short*)outp;
            int half = lane >> 5, l32 = lane & 31;
#pragma unroll
            for (int it = 0; it < 16; it++) {
                int rloc = wave * 32 + it * 2 + half;
                int a = rowA0 + rloc;
                unsigned long long d = *(const unsigned long long*)&Ot[rloc * 136 + l32 * 4];
                if (a < NA)
                    *(unsigned long long*)&O[(size_t)a * NU + rowB0 + l32 * 4] = d;
            }
        } else {
            // fused layer-3 partial dot: per-lane over its 16 c's, quad + wm reduce
            float pn[4] = {0.f, 0.f, 0.f, 0.f};
#pragma unroll
            for (int mt = 0; mt < 4; mt++) {
#pragma unroll
                for (int reg = 0; reg < 4; reg++) {
                    int c = rowA0 + wm * 64 + mt * 16 + quad * 4 + reg;
                    float b = bias[c];
                    float w3c = w3[c];
#pragma unroll
                    for (int nt = 0; nt < 4; nt++) {
                        float v = acc[mt][nt][reg] + b;
                        pn[nt] += w3c * (v / (1.f + __expf(-v)));
                    }
                }
            }
#pragma unroll
            for (int nt = 0; nt < 4; nt++) {
                pn[nt] += __shfl_xor(pn[nt], 16);
                pn[nt] += __shfl_xor(pn[nt], 32);
            }
            __syncthreads();   // As/Bs done; red region safe vs previous tile
            if (quad == 0) {
#pragma unroll
                for (int nt = 0; nt < 4; nt++)
                    red[((wm * 2 + wn) * 4 + nt) * 16 + l16] = pn[nt];
            }
            __syncthreads();
            if (tid < 128) {
                int wn2 = tid >> 6, nt2 = (tid >> 4) & 3, lb = tid & 15;
                float s = red[((0 * 2 + wn2) * 4 + nt2) * 16 + lb]
                        + red[((1 * 2 + wn2) * 4 + nt2) * 16 + lb];
                int a = rowB0 + wn2 * 64 + nt2 * 16 + lb;
                if (a < NA) atomicAdd((float*)outp + a, s);
            }
        }
    }
}

// ---------------- finish: out = scale[Z]*(out + b3) + shift[Z] ----------------
__global__ void k_finish(float* __restrict__ out, const float* __restrict__ b3,
                         const int* __restrict__ Z, const float* __restrict__ scale,
                         const float* __restrict__ shift) {
    int a = blockIdx.x * blockDim.x + threadIdx.x;
    if (a >= NA) return;
    int z = Z[a];
    out[a] = scale[z] * (out[a] + b3[0]) + shift[z];
}

extern "C" void kernel_launch(void* const* d_in, const int* in_sizes, int n_in,
                              void* d_out, int out_size, void* d_ws, size_t ws_size,
                              hipStream_t stream) {
    const float* R    = (const float*)d_in[0];
    const int*   Z    = (const int*)  d_in[1];
    const int*   idx  = (const int*)  d_in[2];
    const float* Wr   = (const float*)d_in[3];
    const float* w1   = (const float*)d_in[4];
    const float* b1   = (const float*)d_in[5];
    const float* w2   = (const float*)d_in[6];
    const float* b2   = (const float*)d_in[7];
    const float* w3   = (const float*)d_in[8];
    const float* b3   = (const float*)d_in[9];
    const float* scale= (const float*)d_in[10];
    const float* shift= (const float*)d_in[11];
    float* out = (float*)d_out;
    char* ws = (char*)d_ws;

    // workspace layout (bytes) — MT region retired (contraction fused)
    int*            gcur   = (int*)  (ws + 0);           // 512
    int*            counts = (int*)  (ws + 512);         // 120000 -> 120576 (padded)
    int*            part   = (int*)  (ws + 120576);      // 5437440 -> 5558016
    int*            plist  = (int*)  (ws + 5558016);     // 15360000 -> 20918016
    unsigned short* gmB    = (unsigned short*)(ws + 32918016);  // 23101440 -> 56019456
    unsigned short* w1T    = (unsigned short*)(ws + 56019456);  // 393216 -> 56412672
    unsigned short* w2T    = (unsigned short*)(ws + 56412672);  // 524288 -> 56936960
    unsigned short* h1B    = (unsigned short*)(ws + 56936960);  // 30801920 -> 87738880
    float*          Wpad   = (float*)(ws + 87738880);    // 2039184 -> 89778064
    float*          Rpad   = (float*)(ws + 89778064);    // 480000 -> 90258064

    hipMemsetAsync(gcur, 0, 512, stream);
    hipMemsetAsync(d_out, 0, NA * sizeof(float), stream);   // layer-3 accumulator

    k_part    <<<256, 256, 0, stream>>>(idx, Z, gcur, part);
    k_csr     <<<235, 256, 0, stream>>>(part, gcur, counts, plist);
    k_prep    <<<(PREP_TOT + 255) / 256, 256, 0, stream>>>(Wr, R, w1, w2, Wpad, Rpad, w1T, w2T);
    k_moments <<<NA / 16, 256, 0, stream>>>(Rpad, Z, Wpad, counts, plist, gmB);

    k_mfma<KP1, 1><<<dim3(NU / 128, 118), 256, 0, stream>>>(gmB, w1T, b1, nullptr, (void*)h1B);
    k_mfma<NU,  2><<<dim3(NU / 128, 118), 256, 0, stream>>>(w2T, h1B, b2, w3, (void*)out);

    k_finish<<<(NA + 255) / 256, 256, 0, stream>>>(out, b3, Z, scale, shift);
}

// Round 15
// 283.581 us; speedup vs baseline: 1.0208x; 1.0208x over previous
//
#include <hip/hip_runtime.h>

#define NA      30000
#define MPAD    30080            // 235 * 128
#define NPAIRS  1200000
#define NB      7
#define NK      5
#define NSP     119
#define NFEAT   360
#define KP1     384              // NFEAT padded to 64
#define NU      512
#define WROW    36               // padded W row (35 -> 36 floats, 144B, 16B aligned)
#define MAXSLOT 120              // plist slots per atom (Poisson(40): P(deg>120) ~ 0)
#define PSTRIDE 128              // plist row stride in ints (alignment)
#define NBK     118              // coarse buckets of 256 atoms (ceil(30000/256))
#define BCAP    11520            // entries per coarse bucket (mean 10240, sd ~101)
#define PPB     4688             // pairs per partition block (256 blocks)
#define NTILE   235              // 128-atom tiles

#define BETTA      1.3611111111111112f     // 49/36
#define RADNORM    0.96481348f             // (2*betta/pi)^0.25
#define SHIFT_STEP 0.7857142857142857f     // 5.5/7
#define PI_OVER_R  0.5235987755982988f     // pi/6
#define INV_SQRT7  0.3779644730092272f
#define RMAXV      6.0f

typedef __attribute__((ext_vector_type(8))) short bf16x8;
typedef __attribute__((ext_vector_type(4))) float f32x4;

__device__ __forceinline__ unsigned short f2b(float x) {
    unsigned u = __float_as_uint(x);
    unsigned r = u + 0x7FFF + ((u >> 16) & 1);   // RNE (inputs are finite)
    return (unsigned short)(r >> 16);
}

// ---------------- phase 1: partition pairs into 118 coarse buckets ----------------
// entry pack: (i&255)<<22 | Zj<<15 | j   (iloc 8b, Zj 7b, j 15b)
__global__ __launch_bounds__(256)
void k_part(const int* __restrict__ idx, const int* __restrict__ Z,
            int* __restrict__ gcur, int* __restrict__ part) {
    __shared__ int hist[NBK];
    __shared__ int base[NBK];
    int tid = threadIdx.x;
    for (int b = tid; b < NBK; b += 256) hist[b] = 0;
    __syncthreads();
    int p0 = blockIdx.x * PPB;
    int p1 = min(p0 + PPB, NPAIRS);
    for (int p = p0 + tid; p < p1; p += 256)
        atomicAdd(&hist[idx[p] >> 8], 1);
    __syncthreads();
    for (int b = tid; b < NBK; b += 256) {
        base[b] = atomicAdd(&gcur[b], hist[b]);
        hist[b] = 0;
    }
    __syncthreads();
    for (int p = p0 + tid; p < p1; p += 256) {
        int i = idx[p];
        int b = i >> 8;
        int j = idx[NPAIRS + p];
        int zj = Z[j];
        int off = base[b] + atomicAdd(&hist[b], 1);
        if (off < BCAP)
            part[b * BCAP + off] = ((i & 255) << 22) | (zj << 15) | j;
    }
}

// ---------------- phase 2: coarse buckets -> dense CSR rows (coalesced writes) ----
__global__ __launch_bounds__(256)
void k_csr(const int* __restrict__ part, const int* __restrict__ gcnt,
           int* __restrict__ counts, int* __restrict__ plist) {
    __shared__ int lp[128 * MAXSLOT];   // 61440 B
    __shared__ int lc[128];
    int tid = threadIdx.x;
    int lane = tid & 63, wave = tid >> 6;
    int w = blockIdx.x;                 // 128-atom window, 0..234
    int cb = w >> 1;                    // coarse bucket
    int par = w & 1;                    // which 128-half of the 256-atom bucket
    for (int t = tid; t < 128; t += 256) lc[t] = 0;
    __syncthreads();
    int n = min(gcnt[cb], BCAP);
    for (int e = tid; e < n; e += 256) {
        int v = part[cb * BCAP + e];
        int iloc = v >> 22;             // 0..255
        if ((iloc >> 7) == par) {
            int i7 = iloc & 127;
            int r = atomicAdd(&lc[i7], 1);
            if (r < MAXSLOT) lp[i7 * MAXSLOT + r] = v & 0x3FFFFF;  // Zj<<15 | j
        }
    }
    __syncthreads();
    for (int t = tid; t < 128; t += 256) {
        int a = w * 128 + t;
        if (a < NA) counts[a] = min(lc[t], MAXSLOT);
    }
    // coalesced row writes: each wave 32 rows (4 waves x 32 = 128 rows)
    for (int rr = 0; rr < 32; rr++) {
        int row = wave * 32 + rr;
        int a = w * 128 + row;
        if (a < NA) {
            for (int c = lane; c < MAXSLOT; c += 64)
                plist[(size_t)a * PSTRIDE + c] = lp[row * MAXSLOT + c];
        }
    }
}

// ---------------- merged prep: Wpad, Rpad, w1T, w2T in one launch ----------------
#define PREP_W   (NSP*NSP*WROW)          // 509796
#define PREP_R   NA                      // 30000
#define PREP_W1  (NU*KP1)                // 196608
#define PREP_W2  (NU*NU)                 // 262144
#define PREP_TOT (PREP_W + PREP_R + PREP_W1 + PREP_W2)
__global__ void k_prep(const float* __restrict__ W, const float* __restrict__ R,
                       const float* __restrict__ w1, const float* __restrict__ w2,
                       float* __restrict__ Wp, float* __restrict__ Rp,
                       unsigned short* __restrict__ w1T, unsigned short* __restrict__ w2T) {
    int i = blockIdx.x * blockDim.x + threadIdx.x;
    if (i < PREP_W) {
        int row = i / WROW, e = i - row * WROW;
        Wp[i] = (e < NK * NB) ? W[row * (NK * NB) + e] : 0.f;
        return;
    }
    i -= PREP_W;
    if (i < PREP_R) {
        f32x4 v = {R[3*i], R[3*i+1], R[3*i+2], 0.f};
        *(f32x4*)&Rp[4*i] = v;
        return;
    }
    i -= PREP_R;
    if (i < PREP_W1) {
        int c = i / KP1, kp = i - c * KP1;
        w1T[i] = (kp < NFEAT) ? f2b(w1[kp * NU + c]) : (unsigned short)0;
        return;
    }
    i -= PREP_W1;
    if (i < PREP_W2) {
        int c = i >> 9, kp = i & 511;
        w2T[i] = f2b(w2[kp * NU + c]);
    }
}

// ---------------- moments: ONE 16-lane group per atom ----------------------------
// 7500 waves (2x the 8-lane TLP), half the serial gather chain per lane, only
// +1 shfl step in the epilogue. MT layout: [100][NA].
// NOTE 1 (R8): launch_bounds min-waves stays 2 — pinning 4 caps VGPRs at 128 and
//         spills acc[100] to scratch (685 MB scratch traffic, 5x slower).
// NOTE 2 (R9): acc[] only with compile-time indices — runtime-indexed access
//         demotes it to scratch (576 MB traffic). Lane q==0 writes all 100.
// NOTE 3 (R10): no MULTI-group pair split (doubles epilogue+fetch: 45 -> 64 us);
//         this is a single wider group.
// NOTE 4 (R14): do NOT fuse contraction into this kernel — 16/64-lane-active
//         contraction quadruples wave-work (46+12 -> 100 us).
__global__ __launch_bounds__(256, 2)
void k_moments(const float* __restrict__ Rp, const int* __restrict__ Z,
               const float* __restrict__ Wp,
               const int* __restrict__ counts,
               const int* __restrict__ plist, float* __restrict__ MT) {
    int tid = blockIdx.x * blockDim.x + threadIdx.x;
    int a = tid >> 4, q = tid & 15;
    if (a >= NA) return;
    f32x4 ri = *(const f32x4*)&Rp[4*a];
    int Zi = Z[a];
    float acc[100];
#pragma unroll
    for (int u = 0; u < 100; u++) acc[u] = 0.f;
    int cnt = min(counts[a], MAXSLOT);
    const int* prow = plist + (size_t)a * PSTRIDE;

    for (int t = q; t < cnt; t += 16) {
        int pk = prow[t];
        int j  = pk & 0x7FFF;
        int Zj = (pk >> 15) & 0x7F;
        f32x4 rj = *(const f32x4*)&Rp[4*j];

        const f32x4* wrow = (const f32x4*)&Wp[(Zi * NSP + Zj) * WROW];
        f32x4 w4[9];
#pragma unroll
        for (int c = 0; c < 9; c++) w4[c] = wrow[c];
        const float* wf = (const float*)w4;

        float dx = rj.x - ri.x, dy = rj.y - ri.y, dz = rj.z - ri.z;
        float d2 = dx*dx + dy*dy + dz*dz + 1e-12f;
        float dr = sqrtf(d2);
        float inv = 1.0f / (dr + 1e-5f);
        float nx = dx*inv, ny = dy*inv, nz = dz*inv;

        float basis[NB];
#pragma unroll
        for (int b = 0; b < NB; b++) {
            float tt = dr - (0.5f + SHIFT_STEP * (float)b);
            basis[b] = RADNORM * __expf(-BETTA * tt * tt);
        }
        float cut = (dr < RMAXV) ? 0.5f * (__cosf(PI_OVER_R * dr) + 1.0f) : 0.0f;
        cut *= INV_SQRT7;
        float rad[NK];
#pragma unroll
        for (int k = 0; k < NK; k++) {
            float s = 0.f;
#pragma unroll
            for (int b = 0; b < NB; b++) s += wf[k*NB + b] * basis[b];
            rad[k] = s * cut;
        }
        float g[20];
        g[0] = 1.f; g[1] = nx; g[2] = ny; g[3] = nz;
        g[4] = nx*nx; g[5] = nx*ny; g[6] = nx*nz; g[7] = ny*ny; g[8] = ny*nz; g[9] = nz*nz;
        g[10] = g[4]*nx; g[11] = g[4]*ny; g[12] = g[4]*nz; g[13] = g[5]*ny; g[14] = g[5]*nz;
        g[15] = g[6]*nz; g[16] = g[7]*ny; g[17] = g[7]*nz; g[18] = g[8]*nz; g[19] = g[9]*nz;
#pragma unroll
        for (int k = 0; k < NK; k++)
#pragma unroll
            for (int u = 0; u < 20; u++)
                acc[k*20 + u] += rad[k] * g[u];
    }
    // reduce within the 16-lane group; lane q==0 holds the sum
#pragma unroll
    for (int u = 0; u < 100; u++) {
        float v = acc[u];
        v += __shfl_xor(v, 1);
        v += __shfl_xor(v, 2);
        v += __shfl_xor(v, 4);
        v += __shfl_xor(v, 8);
        acc[u] = v;
    }
    if (q == 0) {
#pragma unroll
        for (int u = 0; u < 100; u++) MT[u * NA + a] = acc[u];
    }
}

// ---------------- contractions: block = 64 atoms in LDS, 4 waves split features ----
__global__ __launch_bounds__(256)
void k_contract(const float* __restrict__ MT, unsigned short* __restrict__ gmB) {
    __shared__ float M[100 * 64];
    int tid = threadIdx.x;
    int lane = tid & 63;
    int wave = tid >> 6;
    int a0 = blockIdx.x * 64;
    int a = a0 + lane;

    for (int e = tid; e < 6400; e += 256) {
        int u = e >> 6, l = e & 63;
        int aa = a0 + l;
        M[e] = (aa < NA) ? MT[u * NA + aa] : 0.f;
    }
    __syncthreads();

    const int S2[3][3] = {{0,1,2},{1,3,4},{2,4,5}};
    const int S3[3][3][3] = {
        {{0,1,2},{1,3,4},{2,4,5}},
        {{1,3,4},{3,6,7},{4,7,8}},
        {{2,4,5},{4,7,8},{5,8,9}}
    };
    bool ok = (a < NA);
    unsigned short* row = gmB + (size_t)a * KP1;
#define LD(comp) M[(comp) * 64 + lane]

    if (wave == 0) {
        if (ok) {
            for (int k = 0; k < 5; k++) row[k] = f2b(LD(k * 20));
        }
        int f = 5;
        for (int r = 0; r < 5; r++)
            for (int s = r; s < 5; s++) {
                float v = 0.f;
#pragma unroll
                for (int i = 0; i < 3; i++) v += LD(r*20+1+i) * LD(s*20+1+i);
                if (ok) row[f] = f2b(v);
                f++;
            }
        const float W2U[6] = {1,2,2,1,2,1};
        for (int r = 0; r < 5; r++)
            for (int s = r; s < 5; s++) {
                float v = 0.f;
#pragma unroll
                for (int u = 0; u < 6; u++) v += W2U[u] * LD(r*20+4+u) * LD(s*20+4+u);
                if (ok) row[f] = f2b(v);
                f++;
            }
        const float W3U[10] = {1,3,3,3,6,3,1,3,3,1};
        for (int r = 0; r < 5; r++)
            for (int s = r; s < 5; s++) {
                float v = 0.f;
#pragma unroll
                for (int u = 0; u < 10; u++) v += W3U[u] * LD(r*20+10+u) * LD(s*20+10+u);
                if (ok) row[f] = f2b(v);
                f++;
            }
        for (int r = 0; r < 5; r++) {
            float m2r[6];
#pragma unroll
            for (int u = 0; u < 6; u++) m2r[u] = LD(r*20+4+u);
            for (int s = r; s < 5; s++) {
                float m2q[6];
#pragma unroll
                for (int u = 0; u < 6; u++) m2q[u] = LD(s*20+4+u);
                for (int t = s; t < 5; t++) {
                    float m2t[6];
#pragma unroll
                    for (int u = 0; u < 6; u++) m2t[u] = LD(t*20+4+u);
                    float v = 0.f;
#pragma unroll
                    for (int i = 0; i < 3; i++)
#pragma unroll
                        for (int j = 0; j < 3; j++)
#pragma unroll
                            for (int k = 0; k < 3; k++)
                                v += m2r[S2[i][j]] * m2q[S2[i][k]] * m2t[S2[j][k]];
                    if (ok) row[f] = f2b(v);
                    f++;
                }
            }
        }
    } else if (wave == 1) {
        int f = 85;
        for (int r = 0; r < 5; r++) {
            float m1r[3];
#pragma unroll
            for (int i = 0; i < 3; i++) m1r[i] = LD(r*20+1+i);
            for (int s = r; s < 5; s++) {
                float m1q[3];
#pragma unroll
                for (int i = 0; i < 3; i++) m1q[i] = LD(s*20+1+i);
                for (int t = 0; t < 5; t++) {
                    float m2t[6];
#pragma unroll
                    for (int u = 0; u < 6; u++) m2t[u] = LD(t*20+4+u);
                    float v = 0.f;
#pragma unroll
                    for (int i = 0; i < 3; i++)
#pragma unroll
                        for (int j = 0; j < 3; j++)
                            v += m1r[i] * m1q[j] * m2t[S2[i][j]];
                    if (ok) row[f] = f2b(v);
                    f++;
                }
            }
        }
        f = 235;
        for (int r = 0; r < 5; r++) {
            float m3r[10];
#pragma unroll
            for (int u = 0; u < 10; u++) m3r[u] = LD(r*20+10+u);
            for (int s = 0; s < 5; s++) {
                float m2q[6];
#pragma unroll
                for (int u = 0; u < 6; u++) m2q[u] = LD(s*20+4+u);
                float U0 = 0.f, U1 = 0.f, U2 = 0.f;
#pragma unroll
                for (int i = 0; i < 3; i++)
#pragma unroll
                    for (int j = 0; j < 3; j++) {
                        float ww = m2q[S2[i][j]];
                        U0 += m3r[S3[i][j][0]] * ww;
                        U1 += m3r[S3[i][j][1]] * ww;
                        U2 += m3r[S3[i][j][2]] * ww;
                    }
                for (int t = 0; t < 5; t++) {
                    float v = U0 * LD(t*20+1) + U1 * LD(t*20+2) + U2 * LD(t*20+3);
                    if (ok) row[f] = f2b(v);
                    f++;
                }
            }
        }
    } else {
        int pbeg = (wave == 2) ? 0 : 7;
        int pend = (wave == 2) ? 7 : 15;
        int p = 0;
        for (int r = 0; r < 5; r++)
            for (int s = r; s < 5; s++) {
                if (p >= pbeg && p < pend) {
                    float m3r[10], m3q[10];
#pragma unroll
                    for (int u = 0; u < 10; u++) m3r[u] = LD(r*20+10+u);
#pragma unroll
                    for (int u = 0; u < 10; u++) m3q[u] = LD(s*20+10+u);
                    float T[3][3];
#pragma unroll
                    for (int k = 0; k < 3; k++)
#pragma unroll
                        for (int l = 0; l < 3; l++) {
                            float v = 0.f;
#pragma unroll
                            for (int i = 0; i < 3; i++)
#pragma unroll
                                for (int j = 0; j < 3; j++)
                                    v += m3r[S3[i][j][k]] * m3q[S3[i][j][l]];
                            T[k][l] = v;
                        }
                    int f = 160 + p * 5;
                    for (int t = 0; t < 5; t++) {
                        float m2t[6];
#pragma unroll
                        for (int u = 0; u < 6; u++) m2t[u] = LD(t*20+4+u);
                        float v = 0.f;
#pragma unroll
                        for (int k = 0; k < 3; k++)
#pragma unroll
                            for (int l = 0; l < 3; l++)
                                v += T[k][l] * m2t[S2[k][l]];
                        if (ok) row[f + t] = f2b(v);
                    }
                }
                p++;
            }
        if (wave == 3 && ok) {
            for (int z = NFEAT; z < KP1; z++) row[z] = 0;
        }
    }
#undef LD
}

// ---------------- MFMA GEMM, persistent 2 atom-tiles per block -------------------
// MODE 1: A=atoms(gmB), B=units(w1T); h1B bf16 [MPAD][512] = swish(D + bias[col]),
//         written via LDS-staged coalesced stores.
// MODE 2: A=units(w2T), B=atoms(h1B); fused layer-3: atomicAdd w3[c]*swish(D+bias[c])
__device__ __forceinline__ void stage8(const unsigned short* gp, unsigned short* lp) {
    __builtin_amdgcn_global_load_lds(
        (const __attribute__((address_space(1))) unsigned int*)gp,
        (__attribute__((address_space(3))) unsigned int*)lp, 16, 0, 0);
}

template<int KPAD, int MODE>
__global__ __launch_bounds__(256) void k_mfma(const unsigned short* __restrict__ A,
                                              const unsigned short* __restrict__ B,
                                              const float* __restrict__ bias,
                                              const float* __restrict__ w3,
                                              void* __restrict__ outp) {
    // SMEM union: [As 16KB | Bs 16KB | red 1KB]  or  [Ot 128x136 shorts = 34816B]
    __shared__ __align__(16) unsigned char SMEM[35072];
    unsigned short* As = (unsigned short*)SMEM;
    unsigned short* Bs = (unsigned short*)(SMEM + 16384);
    float* red = (float*)(SMEM + 32768);       // [2][2][4][16]
    int tid = threadIdx.x;
    int lane = tid & 63, wave = tid >> 6;
    int wm = wave >> 1, wn = wave & 1;
    int quad = lane >> 4, l16 = lane & 15;
    int lrow = lane >> 3;          // 0..7
    int lchk = lane & 7;           // 16B chunk slot

    for (int t = 0; t < 2; t++) {
        int atile = blockIdx.y * 2 + t;
        if (atile >= NTILE) break;
        int rowA0, rowB0;
        if (MODE == 1) { rowA0 = atile * 128;      rowB0 = blockIdx.x * 128; }
        else           { rowA0 = blockIdx.x * 128; rowB0 = atile * 128; }

        f32x4 acc[4][4];
        f32x4 zero = {0.f, 0.f, 0.f, 0.f};
#pragma unroll
        for (int i = 0; i < 4; i++)
#pragma unroll
            for (int j = 0; j < 4; j++) acc[i][j] = zero;

        for (int k0 = 0; k0 < KPAD; k0 += 64) {
            __syncthreads();
#pragma unroll
            for (int i = 0; i < 4; i++) {
                int r = wave * 32 + i * 8 + lrow;
                int gc = lchk ^ (r & 7);
                stage8(A + (size_t)(rowA0 + r) * KPAD + k0 + gc * 8, &As[(wave * 32 + i * 8) * 64]);
            }
#pragma unroll
            for (int i = 0; i < 4; i++) {
                int r = wave * 32 + i * 8 + lrow;
                int gc = lchk ^ (r & 7);
                stage8(B + (size_t)(rowB0 + r) * KPAD + k0 + gc * 8, &Bs[(wave * 32 + i * 8) * 64]);
            }
            __syncthreads();
#pragma unroll
            for (int s = 0; s < 2; s++) {
                bf16x8 af[4], bfr[4];
#pragma unroll
                for (int mt = 0; mt < 4; mt++) {
                    int r = wm * 64 + mt * 16 + l16;
                    af[mt] = *(const bf16x8*)&As[r * 64 + (((s * 4 + quad) ^ (r & 7)) * 8)];
                }
#pragma unroll
                for (int nt = 0; nt < 4; nt++) {
                    int r = wn * 64 + nt * 16 + l16;
                    bfr[nt] = *(const bf16x8*)&Bs[r * 64 + (((s * 4 + quad) ^ (r & 7)) * 8)];
                }
#pragma unroll
                for (int mt = 0; mt < 4; mt++)
#pragma unroll
                    for (int nt = 0; nt < 4; nt++)
                        acc[mt][nt] = __builtin_amdgcn_mfma_f32_16x16x32_bf16(
                            af[mt], bfr[nt], acc[mt][nt], 0, 0, 0);
            }
        }

        if (MODE == 1) {
            // stage swish output tile in LDS (stride 136 shorts), then coalesced store
            __syncthreads();   // all waves done reading As/Bs
            unsigned short* Ot = (unsigned short*)SMEM;
#pragma unroll
            for (int nt = 0; nt < 4; nt++) {
                int c_loc = wn * 64 + nt * 16 + l16;
                float b = bias[rowB0 + c_loc];
#pragma unroll
                for (int mt = 0; mt < 4; mt++) {
#pragma unroll
                    for (int reg = 0; reg < 4; reg++) {
                        int a_loc = wm * 64 + mt * 16 + quad * 4 + reg;
                        float v = acc[mt][nt][reg] + b;
                        Ot[a_loc * 136 + c_loc] = f2b(v / (1.f + __expf(-v)));
                    }
                }
            }
            __syncthreads();
            unsigned short* O = (unsigned short*)outp;
            int half = lane >> 5, l32 = lane & 31;
#pragma unroll
            for (int it = 0; it < 16; it++) {
                int rloc = wave * 32 + it * 2 + half;
                int a = rowA0 + rloc;
                unsigned long long d = *(const unsigned long long*)&Ot[rloc * 136 + l32 * 4];
                if (a < NA)
                    *(unsigned long long*)&O[(size_t)a * NU + rowB0 + l32 * 4] = d;
            }
        } else {
            // fused layer-3 partial dot: per-lane over its 16 c's, quad + wm reduce
            float pn[4] = {0.f, 0.f, 0.f, 0.f};
#pragma unroll
            for (int mt = 0; mt < 4; mt++) {
#pragma unroll
                for (int reg = 0; reg < 4; reg++) {
                    int c = rowA0 + wm * 64 + mt * 16 + quad * 4 + reg;
                    float b = bias[c];
                    float w3c = w3[c];
#pragma unroll
                    for (int nt = 0; nt < 4; nt++) {
                        float v = acc[mt][nt][reg] + b;
                        pn[nt] += w3c * (v / (1.f + __expf(-v)));
                    }
                }
            }
#pragma unroll
            for (int nt = 0; nt < 4; nt++) {
                pn[nt] += __shfl_xor(pn[nt], 16);
                pn[nt] += __shfl_xor(pn[nt], 32);
            }
            __syncthreads();   // As/Bs done; red region safe vs previous tile
            if (quad == 0) {
#pragma unroll
                for (int nt = 0; nt < 4; nt++)
                    red[((wm * 2 + wn) * 4 + nt) * 16 + l16] = pn[nt];
            }
            __syncthreads();
            if (tid < 128) {
                int wn2 = tid >> 6, nt2 = (tid >> 4) & 3, lb = tid & 15;
                float s = red[((0 * 2 + wn2) * 4 + nt2) * 16 + lb]
                        + red[((1 * 2 + wn2) * 4 + nt2) * 16 + lb];
                int a = rowB0 + wn2 * 64 + nt2 * 16 + lb;
                if (a < NA) atomicAdd((float*)outp + a, s);
            }
        }
    }
}

// ---------------- finish: out = scale[Z]*(out + b3) + shift[Z] ----------------
__global__ void k_finish(float* __restrict__ out, const float* __restrict__ b3,
                         const int* __restrict__ Z, const float* __restrict__ scale,
                         const float* __restrict__ shift) {
    int a = blockIdx.x * blockDim.x + threadIdx.x;
    if (a >= NA) return;
    int z = Z[a];
    out[a] = scale[z] * (out[a] + b3[0]) + shift[z];
}

extern "C" void kernel_launch(void* const* d_in, const int* in_sizes, int n_in,
                              void* d_out, int out_size, void* d_ws, size_t ws_size,
                              hipStream_t stream) {
    const float* R    = (const float*)d_in[0];
    const int*   Z    = (const int*)  d_in[1];
    const int*   idx  = (const int*)  d_in[2];
    const float* Wr   = (const float*)d_in[3];
    const float* w1   = (const float*)d_in[4];
    const float* b1   = (const float*)d_in[5];
    const float* w2   = (const float*)d_in[6];
    const float* b2   = (const float*)d_in[7];
    const float* w3   = (const float*)d_in[8];
    const float* b3   = (const float*)d_in[9];
    const float* scale= (const float*)d_in[10];
    const float* shift= (const float*)d_in[11];
    float* out = (float*)d_out;
    char* ws = (char*)d_ws;

    // workspace layout (bytes)
    int*            gcur   = (int*)  (ws + 0);           // 512
    int*            counts = (int*)  (ws + 512);         // 120000 -> 120576 (padded)
    int*            part   = (int*)  (ws + 120576);      // 5437440 -> 5558016
    int*            plist  = (int*)  (ws + 5558016);     // 15360000 -> 20918016
    float*          MT     = (float*)(ws + 20918016);    // 12000000 -> 32918016
    unsigned short* gmB    = (unsigned short*)(ws + 32918016);  // 23101440 -> 56019456
    unsigned short* w1T    = (unsigned short*)(ws + 56019456);  // 393216 -> 56412672
    unsigned short* w2T    = (unsigned short*)(ws + 56412672);  // 524288 -> 56936960
    unsigned short* h1B    = (unsigned short*)(ws + 56936960);  // 30801920 -> 87738880
    float*          Wpad   = (float*)(ws + 87738880);    // 2039184 -> 89778064
    float*          Rpad   = (float*)(ws + 89778064);    // 480000 -> 90258064

    hipMemsetAsync(gcur, 0, 512, stream);
    hipMemsetAsync(d_out, 0, NA * sizeof(float), stream);   // layer-3 accumulator

    k_part    <<<256, 256, 0, stream>>>(idx, Z, gcur, part);
    k_csr     <<<235, 256, 0, stream>>>(part, gcur, counts, plist);
    k_prep    <<<(PREP_TOT + 255) / 256, 256, 0, stream>>>(Wr, R, w1, w2, Wpad, Rpad, w1T, w2T);
    k_moments <<<(NA * 16 + 255) / 256, 256, 0, stream>>>(Rpad, Z, Wpad, counts, plist, MT);
    k_contract<<<(NA + 63) / 64,       256, 0, stream>>>(MT, gmB);

    k_mfma<KP1, 1><<<dim3(NU / 128, 118), 256, 0, stream>>>(gmB, w1T, b1, nullptr, (void*)h1B);
    k_mfma<NU,  2><<<dim3(NU / 128, 118), 256, 0, stream>>>(w2T, h1B, b2, w3, (void*)out);

    k_finish<<<(NA + 255) / 256, 256, 0, stream>>>(out, b3, Z, scale, shift);
}

// Round 16
// 268.762 us; speedup vs baseline: 1.0771x; 1.0551x over previous
//
#include <hip/hip_runtime.h>

#define NA      30000
#define MPAD    30080            // 235 * 128
#define NPAIRS  1200000
#define NB      7
#define NK      5
#define NSP     119
#define NFEAT   360
#define KP1     384              // NFEAT padded to 64
#define NU      512
#define WROW    36               // padded W row (35 -> 36 floats, 144B, 16B aligned)
#define MAXSLOT 120              // plist slots per atom (Poisson(40): P(deg>120) ~ 0)
#define PSTRIDE 128              // plist row stride in ints (alignment)
#define NBK     118              // coarse buckets of 256 atoms (ceil(30000/256))
#define BCAP    11520            // entries per coarse bucket (mean 10240, sd ~101)
#define PPB     4688             // pairs per partition block (256 blocks)
#define NTILE   235              // 128-atom tiles

#define BETTA      1.3611111111111112f     // 49/36
#define RADNORM    0.96481348f             // (2*betta/pi)^0.25
#define SHIFT_STEP 0.7857142857142857f     // 5.5/7
#define PI_OVER_R  0.5235987755982988f     // pi/6
#define INV_SQRT7  0.3779644730092272f
#define RMAXV      6.0f

typedef __attribute__((ext_vector_type(8))) short bf16x8;
typedef __attribute__((ext_vector_type(4))) float f32x4;
typedef __attribute__((ext_vector_type(2))) float f32x2;

__device__ __forceinline__ unsigned short f2b(float x) {
    unsigned u = __float_as_uint(x);
    unsigned r = u + 0x7FFF + ((u >> 16) & 1);   // RNE (inputs are finite)
    return (unsigned short)(r >> 16);
}

// ---------------- phase 1: partition pairs into 118 coarse buckets ----------------
// entry pack: (i&255)<<22 | Zj<<15 | j   (iloc 8b, Zj 7b, j 15b)
__global__ __launch_bounds__(256)
void k_part(const int* __restrict__ idx, const int* __restrict__ Z,
            int* __restrict__ gcur, int* __restrict__ part) {
    __shared__ int hist[NBK];
    __shared__ int base[NBK];
    int tid = threadIdx.x;
    for (int b = tid; b < NBK; b += 256) hist[b] = 0;
    __syncthreads();
    int p0 = blockIdx.x * PPB;
    int p1 = min(p0 + PPB, NPAIRS);
    for (int p = p0 + tid; p < p1; p += 256)
        atomicAdd(&hist[idx[p] >> 8], 1);
    __syncthreads();
    for (int b = tid; b < NBK; b += 256) {
        base[b] = atomicAdd(&gcur[b], hist[b]);
        hist[b] = 0;
    }
    __syncthreads();
    for (int p = p0 + tid; p < p1; p += 256) {
        int i = idx[p];
        int b = i >> 8;
        int j = idx[NPAIRS + p];
        int zj = Z[j];
        int off = base[b] + atomicAdd(&hist[b], 1);
        if (off < BCAP)
            part[b * BCAP + off] = ((i & 255) << 22) | (zj << 15) | j;
    }
}

// ---------------- phase 2: coarse buckets -> dense CSR rows (coalesced writes) ----
__global__ __launch_bounds__(256)
void k_csr(const int* __restrict__ part, const int* __restrict__ gcnt,
           int* __restrict__ counts, int* __restrict__ plist) {
    __shared__ int lp[128 * MAXSLOT];   // 61440 B
    __shared__ int lc[128];
    int tid = threadIdx.x;
    int lane = tid & 63, wave = tid >> 6;
    int w = blockIdx.x;                 // 128-atom window, 0..234
    int cb = w >> 1;                    // coarse bucket
    int par = w & 1;                    // which 128-half of the 256-atom bucket
    for (int t = tid; t < 128; t += 256) lc[t] = 0;
    __syncthreads();
    int n = min(gcnt[cb], BCAP);
    for (int e = tid; e < n; e += 256) {
        int v = part[cb * BCAP + e];
        int iloc = v >> 22;             // 0..255
        if ((iloc >> 7) == par) {
            int i7 = iloc & 127;
            int r = atomicAdd(&lc[i7], 1);
            if (r < MAXSLOT) lp[i7 * MAXSLOT + r] = v & 0x3FFFFF;  // Zj<<15 | j
        }
    }
    __syncthreads();
    for (int t = tid; t < 128; t += 256) {
        int a = w * 128 + t;
        if (a < NA) counts[a] = min(lc[t], MAXSLOT);
    }
    // coalesced row writes: each wave 32 rows (4 waves x 32 = 128 rows)
    for (int rr = 0; rr < 32; rr++) {
        int row = wave * 32 + rr;
        int a = w * 128 + row;
        if (a < NA) {
            for (int c = lane; c < MAXSLOT; c += 64)
                plist[(size_t)a * PSTRIDE + c] = lp[row * MAXSLOT + c];
        }
    }
}

// ---------------- merged prep: Wpad, Rpad, w1T, w2T in one launch ----------------
#define PREP_W   (NSP*NSP*WROW)          // 509796
#define PREP_R   NA                      // 30000
#define PREP_W1  (NU*KP1)                // 196608
#define PREP_W2  (NU*NU)                 // 262144
#define PREP_TOT (PREP_W + PREP_R + PREP_W1 + PREP_W2)
__global__ void k_prep(const float* __restrict__ W, const float* __restrict__ R,
                       const float* __restrict__ w1, const float* __restrict__ w2,
                       float* __restrict__ Wp, float* __restrict__ Rp,
                       unsigned short* __restrict__ w1T, unsigned short* __restrict__ w2T) {
    int i = blockIdx.x * blockDim.x + threadIdx.x;
    if (i < PREP_W) {
        int row = i / WROW, e = i - row * WROW;
        Wp[i] = (e < NK * NB) ? W[row * (NK * NB) + e] : 0.f;
        return;
    }
    i -= PREP_W;
    if (i < PREP_R) {
        f32x4 v = {R[3*i], R[3*i+1], R[3*i+2], 0.f};
        *(f32x4*)&Rp[4*i] = v;
        return;
    }
    i -= PREP_R;
    if (i < PREP_W1) {
        int c = i / KP1, kp = i - c * KP1;
        w1T[i] = (kp < NFEAT) ? f2b(w1[kp * NU + c]) : (unsigned short)0;
        return;
    }
    i -= PREP_W1;
    if (i < PREP_W2) {
        int c = i >> 9, kp = i & 511;
        w2T[i] = f2b(w2[kp * NU + c]);
    }
}

// ---------------- moments: 8 lanes per atom, packed-fp32 accumulate --------------
// MT layout: [100][NA], u: 0=1, 1..3=n, 4..9=xx,xy,xz,yy,yz,zz, 10..19=3rd order
// acc held as 50 float2 -> v_pk_fma_f32 (gfx90a+ packed fp32): 50 pk-FMA/pair
// instead of 100 scalar FMA; reduction shuffles ride as 64-bit doubles (150 vs 300).
// NOTE 1 (R8): launch_bounds min-waves stays 2 — pinning 4 caps VGPRs at 128 and
//         spills acc to scratch (685 MB scratch traffic, 5x slower).
// NOTE 2 (R9): acc[] only with compile-time indices — runtime-indexed access
//         demotes it to scratch (576 MB traffic). Lane q==0 writes all 100.
// NOTE 3 (R10/R15): 8 lanes/atom is the TLP sweet spot — 2-group split doubles
//         epilogue+fetch (64 us); 16-lane single group exceeds the 4-wave/SIMD
//         VGPR residency cap -> 1.83 dispatch rounds + unamortized epilogue (61 us).
// NOTE 4 (R14): do NOT fuse contraction into this kernel — 16/64-lane-active
//         contraction quadruples wave-work (46+12 -> 100 us).
__global__ __launch_bounds__(256, 2)
void k_moments(const float* __restrict__ Rp, const int* __restrict__ Z,
               const float* __restrict__ Wp,
               const int* __restrict__ counts,
               const int* __restrict__ plist, float* __restrict__ MT) {
    int tid = blockIdx.x * blockDim.x + threadIdx.x;
    int a = tid >> 3, q = tid & 7;
    if (a >= NA) return;
    f32x4 ri = *(const f32x4*)&Rp[4*a];
    int Zi = Z[a];
    f32x2 acc[50];
#pragma unroll
    for (int u = 0; u < 50; u++) acc[u] = (f32x2){0.f, 0.f};
    int cnt = min(counts[a], MAXSLOT);
    const int* prow = plist + (size_t)a * PSTRIDE;

    for (int t = q; t < cnt; t += 8) {
        int pk = prow[t];
        int j  = pk & 0x7FFF;
        int Zj = (pk >> 15) & 0x7F;
        f32x4 rj = *(const f32x4*)&Rp[4*j];

        const f32x4* wrow = (const f32x4*)&Wp[(Zi * NSP + Zj) * WROW];
        f32x4 w4[9];
#pragma unroll
        for (int c = 0; c < 9; c++) w4[c] = wrow[c];
        const float* wf = (const float*)w4;

        float dx = rj.x - ri.x, dy = rj.y - ri.y, dz = rj.z - ri.z;
        float d2 = dx*dx + dy*dy + dz*dz + 1e-12f;
        float dr = sqrtf(d2);
        float inv = 1.0f / (dr + 1e-5f);
        float nx = dx*inv, ny = dy*inv, nz = dz*inv;

        float basis[NB];
#pragma unroll
        for (int b = 0; b < NB; b++) {
            float tt = dr - (0.5f + SHIFT_STEP * (float)b);
            basis[b] = RADNORM * __expf(-BETTA * tt * tt);
        }
        float cut = (dr < RMAXV) ? 0.5f * (__cosf(PI_OVER_R * dr) + 1.0f) : 0.0f;
        cut *= INV_SQRT7;
        float rad[NK];
#pragma unroll
        for (int k = 0; k < NK; k++) {
            float s = 0.f;
#pragma unroll
            for (int b = 0; b < NB; b++) s += wf[k*NB + b] * basis[b];
            rad[k] = s * cut;
        }
        float g[20];
        g[0] = 1.f; g[1] = nx; g[2] = ny; g[3] = nz;
        g[4] = nx*nx; g[5] = nx*ny; g[6] = nx*nz; g[7] = ny*ny; g[8] = ny*nz; g[9] = nz*nz;
        g[10] = g[4]*nx; g[11] = g[4]*ny; g[12] = g[4]*nz; g[13] = g[5]*ny; g[14] = g[5]*nz;
        g[15] = g[6]*nz; g[16] = g[7]*ny; g[17] = g[7]*nz; g[18] = g[8]*nz; g[19] = g[9]*nz;
        f32x2 g2[10];
#pragma unroll
        for (int u = 0; u < 10; u++) g2[u] = (f32x2){g[2*u], g[2*u+1]};
#pragma unroll
        for (int k = 0; k < NK; k++) {
            f32x2 rk = (f32x2){rad[k], rad[k]};
#pragma unroll
            for (int u = 0; u < 10; u++)
                acc[k*10 + u] += rk * g2[u];      // v_pk_fma_f32
        }
    }
    // reduce within the 8-lane group as 64-bit packets; lane q==0 holds the sum
#pragma unroll
    for (int u = 0; u < 50; u++) {
        f32x2 v = acc[u];
        double d = __builtin_bit_cast(double, v);
        d = __shfl_xor(d, 1);
        f32x2 o = __builtin_bit_cast(f32x2, d);
        v += o;
        d = __builtin_bit_cast(double, v);
        d = __shfl_xor(d, 2);
        o = __builtin_bit_cast(f32x2, d);
        v += o;
        d = __builtin_bit_cast(double, v);
        d = __shfl_xor(d, 4);
        o = __builtin_bit_cast(f32x2, d);
        v += o;
        acc[u] = v;
    }
    if (q == 0) {
#pragma unroll
        for (int u = 0; u < 50; u++) {
            MT[(2*u)     * NA + a] = acc[u].x;
            MT[(2*u + 1) * NA + a] = acc[u].y;
        }
    }
}

// ---------------- contractions: block = 64 atoms in LDS, 4 waves split features ----
__global__ __launch_bounds__(256)
void k_contract(const float* __restrict__ MT, unsigned short* __restrict__ gmB) {
    __shared__ float M[100 * 64];
    int tid = threadIdx.x;
    int lane = tid & 63;
    int wave = tid >> 6;
    int a0 = blockIdx.x * 64;
    int a = a0 + lane;

    for (int e = tid; e < 6400; e += 256) {
        int u = e >> 6, l = e & 63;
        int aa = a0 + l;
        M[e] = (aa < NA) ? MT[u * NA + aa] : 0.f;
    }
    __syncthreads();

    const int S2[3][3] = {{0,1,2},{1,3,4},{2,4,5}};
    const int S3[3][3][3] = {
        {{0,1,2},{1,3,4},{2,4,5}},
        {{1,3,4},{3,6,7},{4,7,8}},
        {{2,4,5},{4,7,8},{5,8,9}}
    };
    bool ok = (a < NA);
    unsigned short* row = gmB + (size_t)a * KP1;
#define LD(comp) M[(comp) * 64 + lane]

    if (wave == 0) {
        if (ok) {
            for (int k = 0; k < 5; k++) row[k] = f2b(LD(k * 20));
        }
        int f = 5;
        for (int r = 0; r < 5; r++)
            for (int s = r; s < 5; s++) {
                float v = 0.f;
#pragma unroll
                for (int i = 0; i < 3; i++) v += LD(r*20+1+i) * LD(s*20+1+i);
                if (ok) row[f] = f2b(v);
                f++;
            }
        const float W2U[6] = {1,2,2,1,2,1};
        for (int r = 0; r < 5; r++)
            for (int s = r; s < 5; s++) {
                float v = 0.f;
#pragma unroll
                for (int u = 0; u < 6; u++) v += W2U[u] * LD(r*20+4+u) * LD(s*20+4+u);
                if (ok) row[f] = f2b(v);
                f++;
            }
        const float W3U[10] = {1,3,3,3,6,3,1,3,3,1};
        for (int r = 0; r < 5; r++)
            for (int s = r; s < 5; s++) {
                float v = 0.f;
#pragma unroll
                for (int u = 0; u < 10; u++) v += W3U[u] * LD(r*20+10+u) * LD(s*20+10+u);
                if (ok) row[f] = f2b(v);
                f++;
            }
        for (int r = 0; r < 5; r++) {
            float m2r[6];
#pragma unroll
            for (int u = 0; u < 6; u++) m2r[u] = LD(r*20+4+u);
            for (int s = r; s < 5; s++) {
                float m2q[6];
#pragma unroll
                for (int u = 0; u < 6; u++) m2q[u] = LD(s*20+4+u);
                for (int t = s; t < 5; t++) {
                    float m2t[6];
#pragma unroll
                    for (int u = 0; u < 6; u++) m2t[u] = LD(t*20+4+u);
                    float v = 0.f;
#pragma unroll
                    for (int i = 0; i < 3; i++)
#pragma unroll
                        for (int j = 0; j < 3; j++)
#pragma unroll
                            for (int k = 0; k < 3; k++)
                                v += m2r[S2[i][j]] * m2q[S2[i][k]] * m2t[S2[j][k]];
                    if (ok) row[f] = f2b(v);
                    f++;
                }
            }
        }
    } else if (wave == 1) {
        int f = 85;
        for (int r = 0; r < 5; r++) {
            float m1r[3];
#pragma unroll
            for (int i = 0; i < 3; i++) m1r[i] = LD(r*20+1+i);
            for (int s = r; s < 5; s++) {
                float m1q[3];
#pragma unroll
                for (int i = 0; i < 3; i++) m1q[i] = LD(s*20+1+i);
                for (int t = 0; t < 5; t++) {
                    float m2t[6];
#pragma unroll
                    for (int u = 0; u < 6; u++) m2t[u] = LD(t*20+4+u);
                    float v = 0.f;
#pragma unroll
                    for (int i = 0; i < 3; i++)
#pragma unroll
                        for (int j = 0; j < 3; j++)
                            v += m1r[i] * m1q[j] * m2t[S2[i][j]];
                    if (ok) row[f] = f2b(v);
                    f++;
                }
            }
        }
        f = 235;
        for (int r = 0; r < 5; r++) {
            float m3r[10];
#pragma unroll
            for (int u = 0; u < 10; u++) m3r[u] = LD(r*20+10+u);
            for (int s = 0; s < 5; s++) {
                float m2q[6];
#pragma unroll
                for (int u = 0; u < 6; u++) m2q[u] = LD(s*20+4+u);
                float U0 = 0.f, U1 = 0.f, U2 = 0.f;
#pragma unroll
                for (int i = 0; i < 3; i++)
#pragma unroll
                    for (int j = 0; j < 3; j++) {
                        float ww = m2q[S2[i][j]];
                        U0 += m3r[S3[i][j][0]] * ww;
                        U1 += m3r[S3[i][j][1]] * ww;
                        U2 += m3r[S3[i][j][2]] * ww;
                    }
                for (int t = 0; t < 5; t++) {
                    float v = U0 * LD(t*20+1) + U1 * LD(t*20+2) + U2 * LD(t*20+3);
                    if (ok) row[f] = f2b(v);
                    f++;
                }
            }
        }
    } else {
        int pbeg = (wave == 2) ? 0 : 7;
        int pend = (wave == 2) ? 7 : 15;
        int p = 0;
        for (int r = 0; r < 5; r++)
            for (int s = r; s < 5; s++) {
                if (p >= pbeg && p < pend) {
                    float m3r[10], m3q[10];
#pragma unroll
                    for (int u = 0; u < 10; u++) m3r[u] = LD(r*20+10+u);
#pragma unroll
                    for (int u = 0; u < 10; u++) m3q[u] = LD(s*20+10+u);
                    float T[3][3];
#pragma unroll
                    for (int k = 0; k < 3; k++)
#pragma unroll
                        for (int l = 0; l < 3; l++) {
                            float v = 0.f;
#pragma unroll
                            for (int i = 0; i < 3; i++)
#pragma unroll
                                for (int j = 0; j < 3; j++)
                                    v += m3r[S3[i][j][k]] * m3q[S3[i][j][l]];
                            T[k][l] = v;
                        }
                    int f = 160 + p * 5;
                    for (int t = 0; t < 5; t++) {
                        float m2t[6];
#pragma unroll
                        for (int u = 0; u < 6; u++) m2t[u] = LD(t*20+4+u);
                        float v = 0.f;
#pragma unroll
                        for (int k = 0; k < 3; k++)
#pragma unroll
                            for (int l = 0; l < 3; l++)
                                v += T[k][l] * m2t[S2[k][l]];
                        if (ok) row[f + t] = f2b(v);
                    }
                }
                p++;
            }
        if (wave == 3 && ok) {
            for (int z = NFEAT; z < KP1; z++) row[z] = 0;
        }
    }
#undef LD
}

// ---------------- MFMA GEMM, persistent 2 atom-tiles per block -------------------
// MODE 1: A=atoms(gmB), B=units(w1T); h1B bf16 [MPAD][512] = swish(D + bias[col]),
//         written via LDS-staged coalesced stores.
// MODE 2: A=units(w2T), B=atoms(h1B); fused layer-3: atomicAdd w3[c]*swish(D+bias[c])
__device__ __forceinline__ void stage8(const unsigned short* gp, unsigned short* lp) {
    __builtin_amdgcn_global_load_lds(
        (const __attribute__((address_space(1))) unsigned int*)gp,
        (__attribute__((address_space(3))) unsigned int*)lp, 16, 0, 0);
}

template<int KPAD, int MODE>
__global__ __launch_bounds__(256) void k_mfma(const unsigned short* __restrict__ A,
                                              const unsigned short* __restrict__ B,
                                              const float* __restrict__ bias,
                                              const float* __restrict__ w3,
                                              void* __restrict__ outp) {
    // SMEM union: [As 16KB | Bs 16KB | red 1KB]  or  [Ot 128x136 shorts = 34816B]
    __shared__ __align__(16) unsigned char SMEM[35072];
    unsigned short* As = (unsigned short*)SMEM;
    unsigned short* Bs = (unsigned short*)(SMEM + 16384);
    float* red = (float*)(SMEM + 32768);       // [2][2][4][16]
    int tid = threadIdx.x;
    int lane = tid & 63, wave = tid >> 6;
    int wm = wave >> 1, wn = wave & 1;
    int quad = lane >> 4, l16 = lane & 15;
    int lrow = lane >> 3;          // 0..7
    int lchk = lane & 7;           // 16B chunk slot

    for (int t = 0; t < 2; t++) {
        int atile = blockIdx.y * 2 + t;
        if (atile >= NTILE) break;
        int rowA0, rowB0;
        if (MODE == 1) { rowA0 = atile * 128;      rowB0 = blockIdx.x * 128; }
        else           { rowA0 = blockIdx.x * 128; rowB0 = atile * 128; }

        f32x4 acc[4][4];
        f32x4 zero = {0.f, 0.f, 0.f, 0.f};
#pragma unroll
        for (int i = 0; i < 4; i++)
#pragma unroll
            for (int j = 0; j < 4; j++) acc[i][j] = zero;

        for (int k0 = 0; k0 < KPAD; k0 += 64) {
            __syncthreads();
#pragma unroll
            for (int i = 0; i < 4; i++) {
                int r = wave * 32 + i * 8 + lrow;
                int gc = lchk ^ (r & 7);
                stage8(A + (size_t)(rowA0 + r) * KPAD + k0 + gc * 8, &As[(wave * 32 + i * 8) * 64]);
            }
#pragma unroll
            for (int i = 0; i < 4; i++) {
                int r = wave * 32 + i * 8 + lrow;
                int gc = lchk ^ (r & 7);
                stage8(B + (size_t)(rowB0 + r) * KPAD + k0 + gc * 8, &Bs[(wave * 32 + i * 8) * 64]);
            }
            __syncthreads();
#pragma unroll
            for (int s = 0; s < 2; s++) {
                bf16x8 af[4], bfr[4];
#pragma unroll
                for (int mt = 0; mt < 4; mt++) {
                    int r = wm * 64 + mt * 16 + l16;
                    af[mt] = *(const bf16x8*)&As[r * 64 + (((s * 4 + quad) ^ (r & 7)) * 8)];
                }
#pragma unroll
                for (int nt = 0; nt < 4; nt++) {
                    int r = wn * 64 + nt * 16 + l16;
                    bfr[nt] = *(const bf16x8*)&Bs[r * 64 + (((s * 4 + quad) ^ (r & 7)) * 8)];
                }
#pragma unroll
                for (int mt = 0; mt < 4; mt++)
#pragma unroll
                    for (int nt = 0; nt < 4; nt++)
                        acc[mt][nt] = __builtin_amdgcn_mfma_f32_16x16x32_bf16(
                            af[mt], bfr[nt], acc[mt][nt], 0, 0, 0);
            }
        }

        if (MODE == 1) {
            // stage swish output tile in LDS (stride 136 shorts), then coalesced store
            __syncthreads();   // all waves done reading As/Bs
            unsigned short* Ot = (unsigned short*)SMEM;
#pragma unroll
            for (int nt = 0; nt < 4; nt++) {
                int c_loc = wn * 64 + nt * 16 + l16;
                float b = bias[rowB0 + c_loc];
#pragma unroll
                for (int mt = 0; mt < 4; mt++) {
#pragma unroll
                    for (int reg = 0; reg < 4; reg++) {
                        int a_loc = wm * 64 + mt * 16 + quad * 4 + reg;
                        float v = acc[mt][nt][reg] + b;
                        Ot[a_loc * 136 + c_loc] = f2b(v / (1.f + __expf(-v)));
                    }
                }
            }
            __syncthreads();
            unsigned short* O = (unsigned short*)outp;
            int half = lane >> 5, l32 = lane & 31;
#pragma unroll
            for (int it = 0; it < 16; it++) {
                int rloc = wave * 32 + it * 2 + half;
                int a = rowA0 + rloc;
                unsigned long long d = *(const unsigned long long*)&Ot[rloc * 136 + l32 * 4];
                if (a < NA)
                    *(unsigned long long*)&O[(size_t)a * NU + rowB0 + l32 * 4] = d;
            }
        } else {
            // fused layer-3 partial dot: per-lane over its 16 c's, quad + wm reduce
            float pn[4] = {0.f, 0.f, 0.f, 0.f};
#pragma unroll
            for (int mt = 0; mt < 4; mt++) {
#pragma unroll
                for (int reg = 0; reg < 4; reg++) {
                    int c = rowA0 + wm * 64 + mt * 16 + quad * 4 + reg;
                    float b = bias[c];
                    float w3c = w3[c];
#pragma unroll
                    for (int nt = 0; nt < 4; nt++) {
                        float v = acc[mt][nt][reg] + b;
                        pn[nt] += w3c * (v / (1.f + __expf(-v)));
                    }
                }
            }
#pragma unroll
            for (int nt = 0; nt < 4; nt++) {
                pn[nt] += __shfl_xor(pn[nt], 16);
                pn[nt] += __shfl_xor(pn[nt], 32);
            }
            __syncthreads();   // As/Bs done; red region safe vs previous tile
            if (quad == 0) {
#pragma unroll
                for (int nt = 0; nt < 4; nt++)
                    red[((wm * 2 + wn) * 4 + nt) * 16 + l16] = pn[nt];
            }
            __syncthreads();
            if (tid < 128) {
                int wn2 = tid >> 6, nt2 = (tid >> 4) & 3, lb = tid & 15;
                float s = red[((0 * 2 + wn2) * 4 + nt2) * 16 + lb]
                        + red[((1 * 2 + wn2) * 4 + nt2) * 16 + lb];
                int a = rowB0 + wn2 * 64 + nt2 * 16 + lb;
                if (a < NA) atomicAdd((float*)outp + a, s);
            }
        }
    }
}

// ---------------- finish: out = scale[Z]*(out + b3) + shift[Z] ----------------
__global__ void k_finish(float* __restrict__ out, const float* __restrict__ b3,
                         const int* __restrict__ Z, const float* __restrict__ scale,
                         const float* __restrict__ shift) {
    int a = blockIdx.x * blockDim.x + threadIdx.x;
    if (a >= NA) return;
    int z = Z[a];
    out[a] = scale[z] * (out[a] + b3[0]) + shift[z];
}

extern "C" void kernel_launch(void* const* d_in, const int* in_sizes, int n_in,
                              void* d_out, int out_size, void* d_ws, size_t ws_size,
                              hipStream_t stream) {
    const float* R    = (const float*)d_in[0];
    const int*   Z    = (const int*)  d_in[1];
    const int*   idx  = (const int*)  d_in[2];
    const float* Wr   = (const float*)d_in[3];
    const float* w1   = (const float*)d_in[4];
    const float* b1   = (const float*)d_in[5];
    const float* w2   = (const float*)d_in[6];
    const float* b2   = (const float*)d_in[7];
    const float* w3   = (const float*)d_in[8];
    const float* b3   = (const float*)d_in[9];
    const float* scale= (const float*)d_in[10];
    const float* shift= (const float*)d_in[11];
    float* out = (float*)d_out;
    char* ws = (char*)d_ws;

    // workspace layout (bytes)
    int*            gcur   = (int*)  (ws + 0);           // 512
    int*            counts = (int*)  (ws + 512);         // 120000 -> 120576 (padded)
    int*            part   = (int*)  (ws + 120576);      // 5437440 -> 5558016
    int*            plist  = (int*)  (ws + 5558016);     // 15360000 -> 20918016
    float*          MT     = (float*)(ws + 20918016);    // 12000000 -> 32918016
    unsigned short* gmB    = (unsigned short*)(ws + 32918016);  // 23101440 -> 56019456
    unsigned short* w1T    = (unsigned short*)(ws + 56019456);  // 393216 -> 56412672
    unsigned short* w2T    = (unsigned short*)(ws + 56412672);  // 524288 -> 56936960
    unsigned short* h1B    = (unsigned short*)(ws + 56936960);  // 30801920 -> 87738880
    float*          Wpad   = (float*)(ws + 87738880);    // 2039184 -> 89778064
    float*          Rpad   = (float*)(ws + 89778064);    // 480000 -> 90258064

    hipMemsetAsync(gcur, 0, 512, stream);
    hipMemsetAsync(d_out, 0, NA * sizeof(float), stream);   // layer-3 accumulator

    k_part    <<<256, 256, 0, stream>>>(idx, Z, gcur, part);
    k_csr     <<<235, 256, 0, stream>>>(part, gcur, counts, plist);
    k_prep    <<<(PREP_TOT + 255) / 256, 256, 0, stream>>>(Wr, R, w1, w2, Wpad, Rpad, w1T, w2T);
    k_moments <<<(NA * 8 + 255) / 256, 256, 0, stream>>>(Rpad, Z, Wpad, counts, plist, MT);
    k_contract<<<(NA + 63) / 64,       256, 0, stream>>>(MT, gmB);

    k_mfma<KP1, 1><<<dim3(NU / 128, 118), 256, 0, stream>>>(gmB, w1T, b1, nullptr, (void*)h1B);
    k_mfma<NU,  2><<<dim3(NU / 128, 118), 256, 0, stream>>>(w2T, h1B, b2, w3, (void*)out);

    k_finish<<<(NA + 255) / 256, 256, 0, stream>>>(out, b3, Z, scale, shift);
}

// Round 17
// 258.615 us; speedup vs baseline: 1.1193x; 1.0392x over previous
//
#include <hip/hip_runtime.h>

#define NA      30000
#define MPAD    30080            // 235 * 128
#define NPAIRS  1200000
#define NB      7
#define NK      5
#define NSP     119
#define NFEAT   360
#define KP1     384              // NFEAT padded to 64
#define NU      512
#define WROW    36               // padded W row (35 -> 36 floats, 144B, 16B aligned)
#define MAXSLOT 120              // plist slots per atom (Poisson(40): P(deg>120) ~ 0)
#define PSTRIDE 128              // plist row stride in ints (alignment)
#define NBK     118              // coarse buckets of 256 atoms (ceil(30000/256))
#define BCAP    11520            // entries per coarse bucket (mean 10240, sd ~101)
#define PPB     4688             // pairs per partition block (256 blocks)
#define NTILE   235              // 128-atom tiles

#define BETTA      1.3611111111111112f     // 49/36
#define RADNORM    0.96481348f             // (2*betta/pi)^0.25
#define SHIFT_STEP 0.7857142857142857f     // 5.5/7
#define PI_OVER_R  0.5235987755982988f     // pi/6
#define INV_SQRT7  0.3779644730092272f
#define RMAXV      6.0f

typedef __attribute__((ext_vector_type(8))) short bf16x8;
typedef __attribute__((ext_vector_type(4))) float f32x4;
typedef __attribute__((ext_vector_type(2))) float f32x2;

__device__ __forceinline__ unsigned short f2b(float x) {
    unsigned u = __float_as_uint(x);
    unsigned r = u + 0x7FFF + ((u >> 16) & 1);   // RNE (inputs are finite)
    return (unsigned short)(r >> 16);
}

// ---------------- phase 1: partition pairs into 118 coarse buckets ----------------
// entry pack: (i&255)<<22 | Zj<<15 | j   (iloc 8b, Zj 7b, j 15b)
__global__ __launch_bounds__(256)
void k_part(const int* __restrict__ idx, const int* __restrict__ Z,
            int* __restrict__ gcur, int* __restrict__ part) {
    __shared__ int hist[NBK];
    __shared__ int base[NBK];
    int tid = threadIdx.x;
    for (int b = tid; b < NBK; b += 256) hist[b] = 0;
    __syncthreads();
    int p0 = blockIdx.x * PPB;
    int p1 = min(p0 + PPB, NPAIRS);
    for (int p = p0 + tid; p < p1; p += 256)
        atomicAdd(&hist[idx[p] >> 8], 1);
    __syncthreads();
    for (int b = tid; b < NBK; b += 256) {
        base[b] = atomicAdd(&gcur[b], hist[b]);
        hist[b] = 0;
    }
    __syncthreads();
    for (int p = p0 + tid; p < p1; p += 256) {
        int i = idx[p];
        int b = i >> 8;
        int j = idx[NPAIRS + p];
        int zj = Z[j];
        int off = base[b] + atomicAdd(&hist[b], 1);
        if (off < BCAP)
            part[b * BCAP + off] = ((i & 255) << 22) | (zj << 15) | j;
    }
}

// ---------------- phase 2: coarse buckets -> dense CSR rows (coalesced writes) ----
__global__ __launch_bounds__(256)
void k_csr(const int* __restrict__ part, const int* __restrict__ gcnt,
           int* __restrict__ counts, int* __restrict__ plist) {
    __shared__ int lp[128 * MAXSLOT];   // 61440 B
    __shared__ int lc[128];
    int tid = threadIdx.x;
    int lane = tid & 63, wave = tid >> 6;
    int w = blockIdx.x;                 // 128-atom window, 0..234
    int cb = w >> 1;                    // coarse bucket
    int par = w & 1;                    // which 128-half of the 256-atom bucket
    for (int t = tid; t < 128; t += 256) lc[t] = 0;
    __syncthreads();
    int n = min(gcnt[cb], BCAP);
    for (int e = tid; e < n; e += 256) {
        int v = part[cb * BCAP + e];
        int iloc = v >> 22;             // 0..255
        if ((iloc >> 7) == par) {
            int i7 = iloc & 127;
            int r = atomicAdd(&lc[i7], 1);
            if (r < MAXSLOT) lp[i7 * MAXSLOT + r] = v & 0x3FFFFF;  // Zj<<15 | j
        }
    }
    __syncthreads();
    for (int t = tid; t < 128; t += 256) {
        int a = w * 128 + t;
        if (a < NA) counts[a] = min(lc[t], MAXSLOT);
    }
    // coalesced row writes: each wave 32 rows (4 waves x 32 = 128 rows)
    for (int rr = 0; rr < 32; rr++) {
        int row = wave * 32 + rr;
        int a = w * 128 + row;
        if (a < NA) {
            for (int c = lane; c < MAXSLOT; c += 64)
                plist[(size_t)a * PSTRIDE + c] = lp[row * MAXSLOT + c];
        }
    }
}

// ------- merged prep (runs FIRST): zero gcur + d_out, pad W/R, transpose w1/w2 ----
#define PREP_W   (NSP*NSP*WROW)          // 509796
#define PREP_R   NA                      // 30000
#define PREP_W1  (NU*KP1)                // 196608
#define PREP_W2  (NU*NU)                 // 262144
#define PREP_TOT (PREP_W + PREP_R + PREP_W1 + PREP_W2)
__global__ void k_prep(const float* __restrict__ W, const float* __restrict__ R,
                       const float* __restrict__ w1, const float* __restrict__ w2,
                       float* __restrict__ Wp, float* __restrict__ Rp,
                       unsigned short* __restrict__ w1T, unsigned short* __restrict__ w2T,
                       int* __restrict__ gcur, float* __restrict__ out) {
    int i = blockIdx.x * blockDim.x + threadIdx.x;
    if (i < 128) gcur[i] = 0;            // bucket cursors
    if (i < NA) out[i] = 0.f;            // layer-3 accumulator
    if (i < PREP_W) {
        int row = i / WROW, e = i - row * WROW;
        Wp[i] = (e < NK * NB) ? W[row * (NK * NB) + e] : 0.f;
        return;
    }
    i -= PREP_W;
    if (i < PREP_R) {
        f32x4 v = {R[3*i], R[3*i+1], R[3*i+2], 0.f};
        *(f32x4*)&Rp[4*i] = v;
        return;
    }
    i -= PREP_R;
    if (i < PREP_W1) {
        int c = i / KP1, kp = i - c * KP1;
        w1T[i] = (kp < NFEAT) ? f2b(w1[kp * NU + c]) : (unsigned short)0;
        return;
    }
    i -= PREP_W1;
    if (i < PREP_W2) {
        int c = i >> 9, kp = i & 511;
        w2T[i] = f2b(w2[kp * NU + c]);
    }
}

// ------- fused moments + contraction: 512 threads = 64 atoms x 8 lanes -----------
// Phase A (all 8 waves): R16's pk-fp32 moment accumulation, 8 lanes/atom,
//   butterfly reduce, lane q==0 writes MS[100][65] LDS (stride 65, conflict-free).
// Phase B (waves 0..3, ALL 64 lanes active, lane = atom): the proven k_contract
//   feature split, writing gmB directly. Waves 4..7 exit after the barrier.
// This is NOT R14's trap: contraction lane utilization is identical to the old
// standalone k_contract (64 atoms / 64 lanes); we only save the MT round-trip
// and a ~10us dispatch.
// NOTE 1 (R8): min-waves stays 2 — pinning 4 caps VGPRs at 128, spills acc (5x).
// NOTE 2 (R9): acc[] only with compile-time indices (runtime idx -> scratch).
// NOTE 3 (R10/R15): 8 lanes/atom is the TLP sweet spot (2x8 split: 64us;
//   16-wide: 61us via residency-cap rounds + unamortized epilogue).
__global__ __launch_bounds__(512, 2)
void k_momcon(const float* __restrict__ Rp, const int* __restrict__ Z,
              const float* __restrict__ Wp, const int* __restrict__ counts,
              const int* __restrict__ plist, unsigned short* __restrict__ gmB) {
    __shared__ float MS[100 * 65];      // 26000 B
    int tid = threadIdx.x;
    int g = tid >> 3, q = tid & 7;      // local atom 0..63, lane-in-group
    int a0 = blockIdx.x * 64;
    int a = a0 + g;

    if (a < NA) {
        f32x4 ri = *(const f32x4*)&Rp[4*a];
        int Zi = Z[a];
        f32x2 acc[50];
#pragma unroll
        for (int u = 0; u < 50; u++) acc[u] = (f32x2){0.f, 0.f};
        int cnt = min(counts[a], MAXSLOT);
        const int* prow = plist + (size_t)a * PSTRIDE;

        for (int t = q; t < cnt; t += 8) {
            int pk = prow[t];
            int j  = pk & 0x7FFF;
            int Zj = (pk >> 15) & 0x7F;
            f32x4 rj = *(const f32x4*)&Rp[4*j];

            const f32x4* wrow = (const f32x4*)&Wp[(Zi * NSP + Zj) * WROW];
            f32x4 w4[9];
#pragma unroll
            for (int c = 0; c < 9; c++) w4[c] = wrow[c];
            const float* wf = (const float*)w4;

            float dx = rj.x - ri.x, dy = rj.y - ri.y, dz = rj.z - ri.z;
            float d2 = dx*dx + dy*dy + dz*dz + 1e-12f;
            float dr = sqrtf(d2);
            float inv = 1.0f / (dr + 1e-5f);
            float nx = dx*inv, ny = dy*inv, nz = dz*inv;

            float basis[NB];
#pragma unroll
            for (int b = 0; b < NB; b++) {
                float tt = dr - (0.5f + SHIFT_STEP * (float)b);
                basis[b] = RADNORM * __expf(-BETTA * tt * tt);
            }
            float cut = (dr < RMAXV) ? 0.5f * (__cosf(PI_OVER_R * dr) + 1.0f) : 0.0f;
            cut *= INV_SQRT7;
            float rad[NK];
#pragma unroll
            for (int k = 0; k < NK; k++) {
                float s = 0.f;
#pragma unroll
                for (int b = 0; b < NB; b++) s += wf[k*NB + b] * basis[b];
                rad[k] = s * cut;
            }
            float gg[20];
            gg[0] = 1.f; gg[1] = nx; gg[2] = ny; gg[3] = nz;
            gg[4] = nx*nx; gg[5] = nx*ny; gg[6] = nx*nz; gg[7] = ny*ny; gg[8] = ny*nz; gg[9] = nz*nz;
            gg[10] = gg[4]*nx; gg[11] = gg[4]*ny; gg[12] = gg[4]*nz; gg[13] = gg[5]*ny; gg[14] = gg[5]*nz;
            gg[15] = gg[6]*nz; gg[16] = gg[7]*ny; gg[17] = gg[7]*nz; gg[18] = gg[8]*nz; gg[19] = gg[9]*nz;
            f32x2 g2[10];
#pragma unroll
            for (int u = 0; u < 10; u++) g2[u] = (f32x2){gg[2*u], gg[2*u+1]};
#pragma unroll
            for (int k = 0; k < NK; k++) {
                f32x2 rk = (f32x2){rad[k], rad[k]};
#pragma unroll
                for (int u = 0; u < 10; u++)
                    acc[k*10 + u] += rk * g2[u];      // v_pk_fma_f32
            }
        }
        // reduce within the 8-lane group as 64-bit packets
#pragma unroll
        for (int u = 0; u < 50; u++) {
            f32x2 v = acc[u];
            double d = __builtin_bit_cast(double, v);
            d = __shfl_xor(d, 1);
            v += __builtin_bit_cast(f32x2, d);
            d = __builtin_bit_cast(double, v);
            d = __shfl_xor(d, 2);
            v += __builtin_bit_cast(f32x2, d);
            d = __builtin_bit_cast(double, v);
            d = __shfl_xor(d, 4);
            v += __builtin_bit_cast(f32x2, d);
            acc[u] = v;
        }
        if (q == 0) {
#pragma unroll
            for (int u = 0; u < 50; u++) {
                MS[(2*u)     * 65 + g] = acc[u].x;
                MS[(2*u + 1) * 65 + g] = acc[u].y;
            }
        }
    }
    __syncthreads();

    // ---- phase B: contraction, waves 0..3, lane = atom ----
    int lane = tid & 63, wave = tid >> 6;
    if (wave >= 4) return;              // after the only barrier — legal
    int aB = a0 + lane;
    bool ok = (aB < NA);
    const int S2[3][3] = {{0,1,2},{1,3,4},{2,4,5}};
    const int S3[3][3][3] = {
        {{0,1,2},{1,3,4},{2,4,5}},
        {{1,3,4},{3,6,7},{4,7,8}},
        {{2,4,5},{4,7,8},{5,8,9}}
    };
    unsigned short* row = gmB + (size_t)aB * KP1;
#define LD(comp) MS[(comp) * 65 + lane]

    if (wave == 0) {
        if (ok) {
            for (int k = 0; k < 5; k++) row[k] = f2b(LD(k * 20));
        }
        int f = 5;
        for (int r = 0; r < 5; r++)
            for (int s = r; s < 5; s++) {
                float v = 0.f;
#pragma unroll
                for (int i = 0; i < 3; i++) v += LD(r*20+1+i) * LD(s*20+1+i);
                if (ok) row[f] = f2b(v);
                f++;
            }
        const float W2U[6] = {1,2,2,1,2,1};
        for (int r = 0; r < 5; r++)
            for (int s = r; s < 5; s++) {
                float v = 0.f;
#pragma unroll
                for (int u = 0; u < 6; u++) v += W2U[u] * LD(r*20+4+u) * LD(s*20+4+u);
                if (ok) row[f] = f2b(v);
                f++;
            }
        const float W3U[10] = {1,3,3,3,6,3,1,3,3,1};
        for (int r = 0; r < 5; r++)
            for (int s = r; s < 5; s++) {
                float v = 0.f;
#pragma unroll
                for (int u = 0; u < 10; u++) v += W3U[u] * LD(r*20+10+u) * LD(s*20+10+u);
                if (ok) row[f] = f2b(v);
                f++;
            }
        for (int r = 0; r < 5; r++) {
            float m2r[6];
#pragma unroll
            for (int u = 0; u < 6; u++) m2r[u] = LD(r*20+4+u);
            for (int s = r; s < 5; s++) {
                float m2q[6];
#pragma unroll
                for (int u = 0; u < 6; u++) m2q[u] = LD(s*20+4+u);
                for (int t = s; t < 5; t++) {
                    float m2t[6];
#pragma unroll
                    for (int u = 0; u < 6; u++) m2t[u] = LD(t*20+4+u);
                    float v = 0.f;
#pragma unroll
                    for (int i = 0; i < 3; i++)
#pragma unroll
                        for (int j = 0; j < 3; j++)
#pragma unroll
                            for (int k = 0; k < 3; k++)
                                v += m2r[S2[i][j]] * m2q[S2[i][k]] * m2t[S2[j][k]];
                    if (ok) row[f] = f2b(v);
                    f++;
                }
            }
        }
    } else if (wave == 1) {
        int f = 85;
        for (int r = 0; r < 5; r++) {
            float m1r[3];
#pragma unroll
            for (int i = 0; i < 3; i++) m1r[i] = LD(r*20+1+i);
            for (int s = r; s < 5; s++) {
                float m1q[3];
#pragma unroll
                for (int i = 0; i < 3; i++) m1q[i] = LD(s*20+1+i);
                for (int t = 0; t < 5; t++) {
                    float m2t[6];
#pragma unroll
                    for (int u = 0; u < 6; u++) m2t[u] = LD(t*20+4+u);
                    float v = 0.f;
#pragma unroll
                    for (int i = 0; i < 3; i++)
#pragma unroll
                        for (int j = 0; j < 3; j++)
                            v += m1r[i] * m1q[j] * m2t[S2[i][j]];
                    if (ok) row[f] = f2b(v);
                    f++;
                }
            }
        }
        f = 235;
        for (int r = 0; r < 5; r++) {
            float m3r[10];
#pragma unroll
            for (int u = 0; u < 10; u++) m3r[u] = LD(r*20+10+u);
            for (int s = 0; s < 5; s++) {
                float m2q[6];
#pragma unroll
                for (int u = 0; u < 6; u++) m2q[u] = LD(s*20+4+u);
                float U0 = 0.f, U1 = 0.f, U2 = 0.f;
#pragma unroll
                for (int i = 0; i < 3; i++)
#pragma unroll
                    for (int j = 0; j < 3; j++) {
                        float ww = m2q[S2[i][j]];
                        U0 += m3r[S3[i][j][0]] * ww;
                        U1 += m3r[S3[i][j][1]] * ww;
                        U2 += m3r[S3[i][j][2]] * ww;
                    }
                for (int t = 0; t < 5; t++) {
                    float v = U0 * LD(t*20+1) + U1 * LD(t*20+2) + U2 * LD(t*20+3);
                    if (ok) row[f] = f2b(v);
                    f++;
                }
            }
        }
    } else {
        int pbeg = (wave == 2) ? 0 : 7;
        int pend = (wave == 2) ? 7 : 15;
        int p = 0;
        for (int r = 0; r < 5; r++)
            for (int s = r; s < 5; s++) {
                if (p >= pbeg && p < pend) {
                    float m3r[10], m3q[10];
#pragma unroll
                    for (int u = 0; u < 10; u++) m3r[u] = LD(r*20+10+u);
#pragma unroll
                    for (int u = 0; u < 10; u++) m3q[u] = LD(s*20+10+u);
                    float T[3][3];
#pragma unroll
                    for (int k = 0; k < 3; k++)
#pragma unroll
                        for (int l = 0; l < 3; l++) {
                            float v = 0.f;
#pragma unroll
                            for (int i = 0; i < 3; i++)
#pragma unroll
                                for (int j = 0; j < 3; j++)
                                    v += m3r[S3[i][j][k]] * m3q[S3[i][j][l]];
                            T[k][l] = v;
                        }
                    int f = 160 + p * 5;
                    for (int t = 0; t < 5; t++) {
                        float m2t[6];
#pragma unroll
                        for (int u = 0; u < 6; u++) m2t[u] = LD(t*20+4+u);
                        float v = 0.f;
#pragma unroll
                        for (int k = 0; k < 3; k++)
#pragma unroll
                            for (int l = 0; l < 3; l++)
                                v += T[k][l] * m2t[S2[k][l]];
                        if (ok) row[f + t] = f2b(v);
                    }
                }
                p++;
            }
        if (wave == 3 && ok) {
            for (int z = NFEAT; z < KP1; z++) row[z] = 0;
        }
    }
#undef LD
}

// ---------------- MFMA GEMM, persistent 2 atom-tiles per block -------------------
// MODE 1: A=atoms(gmB), B=units(w1T); h1B bf16 [MPAD][512] = swish(D + bias[col]),
//         written via LDS-staged coalesced stores.
// MODE 2: A=units(w2T), B=atoms(h1B); fused layer-3: atomicAdd w3[c]*swish(D+bias[c])
__device__ __forceinline__ void stage8(const unsigned short* gp, unsigned short* lp) {
    __builtin_amdgcn_global_load_lds(
        (const __attribute__((address_space(1))) unsigned int*)gp,
        (__attribute__((address_space(3))) unsigned int*)lp, 16, 0, 0);
}

template<int KPAD, int MODE>
__global__ __launch_bounds__(256) void k_mfma(const unsigned short* __restrict__ A,
                                              const unsigned short* __restrict__ B,
                                              const float* __restrict__ bias,
                                              const float* __restrict__ w3,
                                              void* __restrict__ outp) {
    // SMEM union: [As 16KB | Bs 16KB | red 1KB]  or  [Ot 128x136 shorts = 34816B]
    __shared__ __align__(16) unsigned char SMEM[35072];
    unsigned short* As = (unsigned short*)SMEM;
    unsigned short* Bs = (unsigned short*)(SMEM + 16384);
    float* red = (float*)(SMEM + 32768);       // [2][2][4][16]
    int tid = threadIdx.x;
    int lane = tid & 63, wave = tid >> 6;
    int wm = wave >> 1, wn = wave & 1;
    int quad = lane >> 4, l16 = lane & 15;
    int lrow = lane >> 3;          // 0..7
    int lchk = lane & 7;           // 16B chunk slot

    for (int t = 0; t < 2; t++) {
        int atile = blockIdx.y * 2 + t;
        if (atile >= NTILE) break;
        int rowA0, rowB0;
        if (MODE == 1) { rowA0 = atile * 128;      rowB0 = blockIdx.x * 128; }
        else           { rowA0 = blockIdx.x * 128; rowB0 = atile * 128; }

        f32x4 acc[4][4];
        f32x4 zero = {0.f, 0.f, 0.f, 0.f};
#pragma unroll
        for (int i = 0; i < 4; i++)
#pragma unroll
            for (int j = 0; j < 4; j++) acc[i][j] = zero;

        for (int k0 = 0; k0 < KPAD; k0 += 64) {
            __syncthreads();
#pragma unroll
            for (int i = 0; i < 4; i++) {
                int r = wave * 32 + i * 8 + lrow;
                int gc = lchk ^ (r & 7);
                stage8(A + (size_t)(rowA0 + r) * KPAD + k0 + gc * 8, &As[(wave * 32 + i * 8) * 64]);
            }
#pragma unroll
            for (int i = 0; i < 4; i++) {
                int r = wave * 32 + i * 8 + lrow;
                int gc = lchk ^ (r & 7);
                stage8(B + (size_t)(rowB0 + r) * KPAD + k0 + gc * 8, &Bs[(wave * 32 + i * 8) * 64]);
            }
            __syncthreads();
#pragma unroll
            for (int s = 0; s < 2; s++) {
                bf16x8 af[4], bfr[4];
#pragma unroll
                for (int mt = 0; mt < 4; mt++) {
                    int r = wm * 64 + mt * 16 + l16;
                    af[mt] = *(const bf16x8*)&As[r * 64 + (((s * 4 + quad) ^ (r & 7)) * 8)];
                }
#pragma unroll
                for (int nt = 0; nt < 4; nt++) {
                    int r = wn * 64 + nt * 16 + l16;
                    bfr[nt] = *(const bf16x8*)&Bs[r * 64 + (((s * 4 + quad) ^ (r & 7)) * 8)];
                }
#pragma unroll
                for (int mt = 0; mt < 4; mt++)
#pragma unroll
                    for (int nt = 0; nt < 4; nt++)
                        acc[mt][nt] = __builtin_amdgcn_mfma_f32_16x16x32_bf16(
                            af[mt], bfr[nt], acc[mt][nt], 0, 0, 0);
            }
        }

        if (MODE == 1) {
            // stage swish output tile in LDS (stride 136 shorts), then coalesced store
            __syncthreads();   // all waves done reading As/Bs
            unsigned short* Ot = (unsigned short*)SMEM;
#pragma unroll
            for (int nt = 0; nt < 4; nt++) {
                int c_loc = wn * 64 + nt * 16 + l16;
                float b = bias[rowB0 + c_loc];
#pragma unroll
                for (int mt = 0; mt < 4; mt++) {
#pragma unroll
                    for (int reg = 0; reg < 4; reg++) {
                        int a_loc = wm * 64 + mt * 16 + quad * 4 + reg;
                        float v = acc[mt][nt][reg] + b;
                        Ot[a_loc * 136 + c_loc] = f2b(v / (1.f + __expf(-v)));
                    }
                }
            }
            __syncthreads();
            unsigned short* O = (unsigned short*)outp;
            int half = lane >> 5, l32 = lane & 31;
#pragma unroll
            for (int it = 0; it < 16; it++) {
                int rloc = wave * 32 + it * 2 + half;
                int a = rowA0 + rloc;
                unsigned long long d = *(const unsigned long long*)&Ot[rloc * 136 + l32 * 4];
                if (a < NA)
                    *(unsigned long long*)&O[(size_t)a * NU + rowB0 + l32 * 4] = d;
            }
        } else {
            // fused layer-3 partial dot: per-lane over its 16 c's, quad + wm reduce
            float pn[4] = {0.f, 0.f, 0.f, 0.f};
#pragma unroll
            for (int mt = 0; mt < 4; mt++) {
#pragma unroll
                for (int reg = 0; reg < 4; reg++) {
                    int c = rowA0 + wm * 64 + mt * 16 + quad * 4 + reg;
                    float b = bias[c];
                    float w3c = w3[c];
#pragma unroll
                    for (int nt = 0; nt < 4; nt++) {
                        float v = acc[mt][nt][reg] + b;
                        pn[nt] += w3c * (v / (1.f + __expf(-v)));
                    }
                }
            }
#pragma unroll
            for (int nt = 0; nt < 4; nt++) {
                pn[nt] += __shfl_xor(pn[nt], 16);
                pn[nt] += __shfl_xor(pn[nt], 32);
            }
            __syncthreads();   // As/Bs done; red region safe vs previous tile
            if (quad == 0) {
#pragma unroll
                for (int nt = 0; nt < 4; nt++)
                    red[((wm * 2 + wn) * 4 + nt) * 16 + l16] = pn[nt];
            }
            __syncthreads();
            if (tid < 128) {
                int wn2 = tid >> 6, nt2 = (tid >> 4) & 3, lb = tid & 15;
                float s = red[((0 * 2 + wn2) * 4 + nt2) * 16 + lb]
                        + red[((1 * 2 + wn2) * 4 + nt2) * 16 + lb];
                int a = rowB0 + wn2 * 64 + nt2 * 16 + lb;
                if (a < NA) atomicAdd((float*)outp + a, s);
            }
        }
    }
}

// ---------------- finish: out = scale[Z]*(out + b3) + shift[Z] ----------------
__global__ void k_finish(float* __restrict__ out, const float* __restrict__ b3,
                         const int* __restrict__ Z, const float* __restrict__ scale,
                         const float* __restrict__ shift) {
    int a = blockIdx.x * blockDim.x + threadIdx.x;
    if (a >= NA) return;
    int z = Z[a];
    out[a] = scale[z] * (out[a] + b3[0]) + shift[z];
}

extern "C" void kernel_launch(void* const* d_in, const int* in_sizes, int n_in,
                              void* d_out, int out_size, void* d_ws, size_t ws_size,
                              hipStream_t stream) {
    const float* R    = (const float*)d_in[0];
    const int*   Z    = (const int*)  d_in[1];
    const int*   idx  = (const int*)  d_in[2];
    const float* Wr   = (const float*)d_in[3];
    const float* w1   = (const float*)d_in[4];
    const float* b1   = (const float*)d_in[5];
    const float* w2   = (const float*)d_in[6];
    const float* b2   = (const float*)d_in[7];
    const float* w3   = (const float*)d_in[8];
    const float* b3   = (const float*)d_in[9];
    const float* scale= (const float*)d_in[10];
    const float* shift= (const float*)d_in[11];
    float* out = (float*)d_out;
    char* ws = (char*)d_ws;

    // workspace layout (bytes)
    int*            gcur   = (int*)  (ws + 0);           // 512
    int*            counts = (int*)  (ws + 512);         // 120000 -> 120576 (padded)
    int*            part   = (int*)  (ws + 120576);      // 5437440 -> 5558016
    int*            plist  = (int*)  (ws + 5558016);     // 15360000 -> 20918016
    unsigned short* gmB    = (unsigned short*)(ws + 32918016);  // 23101440 -> 56019456
    unsigned short* w1T    = (unsigned short*)(ws + 56019456);  // 393216 -> 56412672
    unsigned short* w2T    = (unsigned short*)(ws + 56412672);  // 524288 -> 56936960
    unsigned short* h1B    = (unsigned short*)(ws + 56936960);  // 30801920 -> 87738880
    float*          Wpad   = (float*)(ws + 87738880);    // 2039184 -> 89778064
    float*          Rpad   = (float*)(ws + 89778064);    // 480000 -> 90258064

    // 7 graph nodes (was 10): prep(+zeros), part, csr, momcon, gemm1, gemm2, finish
    k_prep   <<<(PREP_TOT + 255) / 256, 256, 0, stream>>>(Wr, R, w1, w2, Wpad, Rpad,
                                                          w1T, w2T, gcur, out);
    k_part   <<<256, 256, 0, stream>>>(idx, Z, gcur, part);
    k_csr    <<<235, 256, 0, stream>>>(part, gcur, counts, plist);
    k_momcon <<<(NA + 63) / 64, 512, 0, stream>>>(Rpad, Z, Wpad, counts, plist, gmB);

    k_mfma<KP1, 1><<<dim3(NU / 128, 118), 256, 0, stream>>>(gmB, w1T, b1, nullptr, (void*)h1B);
    k_mfma<NU,  2><<<dim3(NU / 128, 118), 256, 0, stream>>>(w2T, h1B, b2, w3, (void*)out);

    k_finish<<<(NA + 255) / 256, 256, 0, stream>>>(out, b3, Z, scale, shift);
}